// Round 6
// baseline (221.901 us; speedup 1.0000x reference)
//
#include <hip/hip_runtime.h>

// ---------- types ----------
typedef __bf16 bf16x8 __attribute__((ext_vector_type(8)));
typedef float  f32x4  __attribute__((ext_vector_type(4)));

__device__ __forceinline__ unsigned short f2bf(float f) {
    union { float f; unsigned int u; } x; x.f = f;
    unsigned int r = (x.u + 0x7FFFu + ((x.u >> 16) & 1u)) >> 16;  // RNE
    return (unsigned short)r;
}

// async global->LDS, 16B per lane; LDS dst is wave-uniform base + lane*16
typedef const __attribute__((address_space(1))) unsigned short gu16;
typedef __attribute__((address_space(3)))       unsigned short lu16;
__device__ __forceinline__ void gl_lds16(const unsigned short* g, unsigned short* l) {
    __builtin_amdgcn_global_load_lds((gu16*)g, (lu16*)l, 16, 0, 0);
}

// ==========================================================================
// ========= 2-phase x 3-buffer GEMM core: BM=128, BN=256, BK=64 ============
// 8 waves (2M x 4N), 512 threads. LDS 144 KB = 3 buffers x 48 KB:
//   buf*24576: A [128 rows][64 k] (8192 ushorts) | B [256 rows][64 k] (16384)
// Per K-tile: 2 phases x 16 MFMA (template-weight). Staging DEPTH 2:
// tile t+2 staged during iter t (B halves in ph1 = 4 loads, A in ph2 = 2),
// so issue->consume distance = 2 tiles (~1100 cyc) > ~900 cyc HBM latency.
// Counted vmcnt(6) at end of each iter retires exactly tile t+1 (FIFO
// ledger: prologue 12 issued, drain 6 = t0; steady 6 outstanding = t+2).
// vmcnt(0) only at iter NT-2. Chunk-XOR swizzle both sides (rule #21):
// source chunk ^= ((lane>>5)&1)<<1 (row bit2), read chunk ^= ((l16>>2)&1)<<1.
// Buffer hazard: t+2 writes buf (t+2)%3 whose last reader (tile t-1)
// finished before iter t-1's end barrier.
// ==========================================================================
__device__ __forceinline__ void stageB23(
    const unsigned short* __restrict__ Bb, int ldb,
    unsigned short* LB, int t, int buf, int wave, int lane)
{
    const int kc = t * 64 + (((lane & 7) ^ ((lane >> 5) << 1)) << 3);
    unsigned short* dst = LB + buf * 24576 + 8192 + wave * 512;
    const int R = wave * 8 + (lane >> 3);
    gl_lds16(Bb + (long)R * ldb + kc,         dst);
    gl_lds16(Bb + (long)(R + 64) * ldb + kc,  dst + 4096);
    gl_lds16(Bb + (long)(R + 128) * ldb + kc, dst + 8192);
    gl_lds16(Bb + (long)(R + 192) * ldb + kc, dst + 12288);
}
__device__ __forceinline__ void stageA23(
    const unsigned short* __restrict__ Ab, int lda,
    unsigned short* LB, int t, int buf, int wave, int lane)
{
    const int kc = t * 64 + (((lane & 7) ^ ((lane >> 5) << 1)) << 3);
    unsigned short* dst = LB + buf * 24576 + wave * 512;
    const int R = wave * 8 + (lane >> 3);
    gl_lds16(Ab + (long)R * lda + kc,        dst);
    gl_lds16(Ab + (long)(R + 64) * lda + kc, dst + 4096);
}

template<int NT>   // K-tiles of 64, NT >= 3
__device__ __forceinline__ void gemm23_core(
    const unsigned short* __restrict__ Ab, int lda,
    const unsigned short* __restrict__ Bb, int ldb,
    f32x4 (&acc)[4][4], unsigned short* LB)
{
    const int tid  = threadIdx.x;
    const int lane = tid & 63;
    const int wave = tid >> 6;
    const int wM   = wave >> 2;
    const int wN   = wave & 3;
    const int l16  = lane & 15;
    const int quad = lane >> 4;
    const int ckx  = quad ^ (((l16 >> 2) & 1) << 1);
    const int aoff = (wM * 64 + l16) * 64 + ckx * 8;            // + buf*24576 + mi*1024 + kk*32
    const int boff = 8192 + (wN * 64 + l16) * 64 + ckx * 8;     // + buf*24576 + ni*1024 + kk*32

    stageB23(Bb, ldb, LB, 0, 0, wave, lane);
    stageA23(Ab, lda, LB, 0, 0, wave, lane);
    stageB23(Bb, ldb, LB, 1, 1, wave, lane);
    stageA23(Ab, lda, LB, 1, 1, wave, lane);
    asm volatile("s_waitcnt vmcnt(6)" ::: "memory");
    __builtin_amdgcn_s_barrier();
    __builtin_amdgcn_sched_barrier(0);

    bf16x8 af[2][2], bf[4][2];

#define RD_A23(buf, mh)                                                       \
    _Pragma("unroll")                                                         \
    for (int m = 0; m < 2; ++m)                                               \
        _Pragma("unroll")                                                     \
        for (int kk = 0; kk < 2; ++kk)                                        \
            af[m][kk] = *(const bf16x8*)&LB[(buf) * 24576 + aoff + ((mh) * 2 + m) * 1024 + kk * 32];
#define RD_B23(buf)                                                           \
    _Pragma("unroll")                                                         \
    for (int n = 0; n < 4; ++n)                                               \
        _Pragma("unroll")                                                     \
        for (int kk = 0; kk < 2; ++kk)                                        \
            bf[n][kk] = *(const bf16x8*)&LB[(buf) * 24576 + boff + n * 1024 + kk * 32];
#define MF23(mh)                                                              \
    __builtin_amdgcn_s_setprio(1);                                            \
    _Pragma("unroll")                                                         \
    for (int m = 0; m < 2; ++m)                                               \
        _Pragma("unroll")                                                     \
        for (int n = 0; n < 4; ++n)                                           \
            _Pragma("unroll")                                                 \
            for (int kk = 0; kk < 2; ++kk)                                    \
                acc[(mh) * 2 + m][n] = __builtin_amdgcn_mfma_f32_16x16x32_bf16( \
                    af[m][kk], bf[n][kk], acc[(mh) * 2 + m][n], 0, 0, 0);     \
    __builtin_amdgcn_s_setprio(0);
#define BARS23 do { __builtin_amdgcn_s_barrier(); __builtin_amdgcn_sched_barrier(0); } while (0)
#define LGW23  do { asm volatile("s_waitcnt lgkmcnt(0)" ::: "memory"); __builtin_amdgcn_sched_barrier(0); } while (0)

    int b = 0, b2 = 2;
    for (int t = 0; t < NT; ++t) {
        // ---- phase 1: read B + A(mh0) of tile t; stage B of tile t+2
        RD_B23(b) RD_A23(b, 0)
        if (t + 2 < NT) stageB23(Bb, ldb, LB, t + 2, b2, wave, lane);
        BARS23; LGW23;
        MF23(0)                               // 16 MFMA
        BARS23;
        // ---- phase 2: read A(mh1); stage A of tile t+2; counted wait
        RD_A23(b, 1)
        if (t + 2 < NT) stageA23(Ab, lda, LB, t + 2, b2, wave, lane);
        BARS23; LGW23;
        MF23(1)                               // 16 MFMA
        if (t + 2 < NT) { asm volatile("s_waitcnt vmcnt(6)" ::: "memory"); }
        else            { asm volatile("s_waitcnt vmcnt(0)" ::: "memory"); }
        BARS23;
        b  = (b == 2)  ? 0 : b + 1;
        b2 = (b2 == 2) ? 0 : b2 + 1;
    }
#undef RD_A23
#undef RD_B23
#undef MF23
#undef BARS23
#undef LGW23
}

// ==========================================================================
// ============== 8-phase BMH=2 core (p8 only — proven template) ============
// ==========================================================================
template<int NT, int BMH>
__device__ __forceinline__ void stage8g(
    const unsigned short* __restrict__ Ab, int lda,
    const unsigned short* __restrict__ Bb, int ldb,
    unsigned short* LB, int s, int wave, int lane)
{
    if (s >= 4 * NT) return;
    const int tau  = s >> 2;
    const int pi   = s & 3;          // 0:B0 1:B1 2:A0 3:A1
    const int half = pi & 1;
    const int kc   = tau * 64 + (((lane & 7) ^ ((lane >> 5) << 1)) << 3);
    if (pi >= 2) {
        unsigned short* dst = LB + (tau & 1) * (BMH * 8192) + half * (BMH * 4096) + wave * 512;
        const int R = half * (BMH * 64) + wave * 8 + (lane >> 3);
        gl_lds16(Ab + (long)R * lda + kc, dst);
        if constexpr (BMH == 2) gl_lds16(Ab + (long)(R + 64) * lda + kc, dst + 4096);
    } else {
        unsigned short* dst = LB + (BMH * 16384) + (tau & 1) * 16384 + half * 8192 + wave * 512;
        const int R = half * 128 + wave * 8 + (lane >> 3);
        gl_lds16(Bb + (long)R * ldb + kc, dst);
        gl_lds16(Bb + (long)(R + 64) * ldb + kc, dst + 4096);
    }
}

template<int NT, int BMH>   // NT = K/64, even
__device__ __forceinline__ void gemm8_core(
    const unsigned short* __restrict__ Ab, int lda,
    const unsigned short* __restrict__ Bb, int ldb,
    f32x4 (&acc)[4 * BMH][4], unsigned short* LB)
{
    const int tid  = threadIdx.x;
    const int lane = tid & 63;
    const int wave = tid >> 6;
    const int wM   = wave >> 2;
    const int wN   = wave & 3;
    const int l16  = lane & 15;
    const int quad = lane >> 4;
    const int ckx  = quad ^ (((l16 >> 2) & 1) << 1);
    const int aoff = wM * (BMH * 4096) + l16 * 64 + ckx * 8;
    const int boff = BMH * 16384 + (wN >> 1) * 8192 + ((wN & 1) * 64 + l16) * 64 + ckx * 8;

#define VMW do { if constexpr (BMH == 2) asm volatile("s_waitcnt vmcnt(6)" ::: "memory"); \
                 else                    asm volatile("s_waitcnt vmcnt(5)" ::: "memory"); } while (0)

    #pragma unroll
    for (int s = 0; s < 7; ++s)
        stage8g<NT, BMH>(Ab, lda, Bb, ldb, LB, s, wave, lane);
    VMW;
    __builtin_amdgcn_s_barrier();
    __builtin_amdgcn_sched_barrier(0);

    bf16x8 af[2 * BMH][2], bf[4][2];

#define RD_A(buf, mh)                                                         \
    _Pragma("unroll")                                                         \
    for (int m = 0; m < 2 * BMH; ++m)                                         \
        _Pragma("unroll")                                                     \
        for (int kk = 0; kk < 2; ++kk)                                        \
            af[m][kk] = *(const bf16x8*)&LB[(buf) * (BMH * 8192) + aoff + ((mh) * 2 * BMH + m) * 1024 + kk * 32];
#define RD_B(buf)                                                             \
    _Pragma("unroll")                                                         \
    for (int n = 0; n < 4; ++n)                                               \
        _Pragma("unroll")                                                     \
        for (int kk = 0; kk < 2; ++kk)                                        \
            bf[n][kk] = *(const bf16x8*)&LB[(buf) * 16384 + boff + n * 1024 + kk * 32];
#define MF(mh, nh)                                                            \
    __builtin_amdgcn_s_setprio(1);                                            \
    _Pragma("unroll")                                                         \
    for (int m = 0; m < 2 * BMH; ++m)                                         \
        _Pragma("unroll")                                                     \
        for (int n = 0; n < 2; ++n)                                           \
            _Pragma("unroll")                                                 \
            for (int kk = 0; kk < 2; ++kk)                                    \
                acc[(mh) * 2 * BMH + m][(nh) * 2 + n] = __builtin_amdgcn_mfma_f32_16x16x32_bf16( \
                    af[m][kk], bf[(nh) * 2 + n][kk], acc[(mh) * 2 * BMH + m][(nh) * 2 + n], 0, 0, 0); \
    __builtin_amdgcn_s_setprio(0);
#define BARS do { __builtin_amdgcn_s_barrier(); __builtin_amdgcn_sched_barrier(0); } while (0)
#define LGW  do { asm volatile("s_waitcnt lgkmcnt(0)" ::: "memory"); __builtin_amdgcn_sched_barrier(0); } while (0)

    const int NITER = NT / 2;
    for (int i = 0; i < NITER; ++i) {
        const int s0 = 6 + 8 * i;
        RD_B(0) RD_A(0, 0)
        stage8g<NT, BMH>(Ab, lda, Bb, ldb, LB, s0 + 1, wave, lane);
        BARS; LGW;
        MF(0, 0)
        BARS;
        stage8g<NT, BMH>(Ab, lda, Bb, ldb, LB, s0 + 2, wave, lane);
        BARS;
        MF(0, 1)
        BARS;
        RD_A(0, 1)
        stage8g<NT, BMH>(Ab, lda, Bb, ldb, LB, s0 + 3, wave, lane);
        BARS; LGW;
        MF(1, 0)
        BARS;
        stage8g<NT, BMH>(Ab, lda, Bb, ldb, LB, s0 + 4, wave, lane);
        BARS;
        MF(1, 1)
        if (i == NITER - 1) { asm volatile("s_waitcnt vmcnt(0)" ::: "memory"); }
        else                { VMW; }
        BARS;
        RD_B(1) RD_A(1, 0)
        stage8g<NT, BMH>(Ab, lda, Bb, ldb, LB, s0 + 5, wave, lane);
        BARS; LGW;
        MF(0, 0)
        BARS;
        stage8g<NT, BMH>(Ab, lda, Bb, ldb, LB, s0 + 6, wave, lane);
        BARS;
        MF(0, 1)
        BARS;
        RD_A(1, 1)
        stage8g<NT, BMH>(Ab, lda, Bb, ldb, LB, s0 + 7, wave, lane);
        BARS; LGW;
        MF(1, 0)
        BARS;
        stage8g<NT, BMH>(Ab, lda, Bb, ldb, LB, s0 + 8, wave, lane);
        BARS;
        MF(1, 1)
        if (i < NITER - 1) { VMW; }
        BARS;
    }
#undef RD_A
#undef RD_B
#undef MF
#undef BARS
#undef LGW
#undef VMW
}

// ==========================================================================
// P' kernel (256^2 8-phase): Sb[i][j] = exp(alpha * q.k), row sums -> lsum
// grid (4,4,16) = 256 blocks, 512 threads.
// ==========================================================================
__global__ __launch_bounds__(512, 2) void p8_k(
    const unsigned short* __restrict__ qT,
    const unsigned short* __restrict__ kT,
    unsigned short* __restrict__ Sb,
    float* __restrict__ lsum,
    float alpha)
{
    __shared__ __align__(16) unsigned short LB[65536];
    const int z = blockIdx.z;
    const unsigned short* Ab = qT + (long)z * 524288 + (long)(blockIdx.y * 256) * 512;
    const unsigned short* Bb = kT + (long)z * 524288 + (long)(blockIdx.x * 256) * 512;
    f32x4 acc[8][4] = {};
    gemm8_core<8, 2>(Ab, 512, Bb, 512, acc, LB);

    const int lane = threadIdx.x & 63, wave = threadIdx.x >> 6;
    const int wM = wave >> 2, wN = wave & 3;
    const int l16 = lane & 15, quad = lane >> 4;
    const int gm0 = blockIdx.y * 256 + wM * 128;
    const int gn0 = blockIdx.x * 256 + wN * 64;
    unsigned short* scr = LB + wave * 8192;     // 128 rows x 64 ushort, chunk-XOR

    float rs[8][4];
    #pragma unroll
    for (int mi = 0; mi < 8; ++mi) { rs[mi][0] = rs[mi][1] = rs[mi][2] = rs[mi][3] = 0.f; }
    #pragma unroll
    for (int mi = 0; mi < 8; ++mi)
        #pragma unroll
        for (int ni = 0; ni < 4; ++ni) {
            f32x4 v = acc[mi][ni];
            #pragma unroll
            for (int r = 0; r < 4; ++r) {
                float e = __expf(v[r] * alpha);
                rs[mi][r] += e;
                const int row = mi * 16 + quad * 4 + r;
                const int col = ni * 16 + l16;
                scr[row * 64 + (((col >> 3) ^ (row & 7)) << 3) + (col & 7)] = f2bf(e);
            }
        }
    #pragma unroll
    for (int mi = 0; mi < 8; ++mi)
        #pragma unroll
        for (int r = 0; r < 4; ++r) {
            float s = rs[mi][r];
            s += __shfl_xor(s, 1); s += __shfl_xor(s, 2);
            s += __shfl_xor(s, 4); s += __shfl_xor(s, 8);
            if (l16 == 0)
                atomicAdd(&lsum[(long)z * 1024 + gm0 + mi * 16 + quad * 4 + r], s);
        }
    unsigned short* dst = Sb + (long)z * 1048576;
    #pragma unroll
    for (int it = 0; it < 16; ++it) {
        const int row = it * 8 + (lane >> 3);
        const int ck  = lane & 7;
        uint4 vv = *(uint4*)&scr[row * 64 + ((ck ^ (row & 7)) << 3)];
        *(uint4*)&dst[(long)(gm0 + row) * 1024 + gn0 + ck * 8] = vv;
    }
}

// ==========================================================================
// Fused QKV (128x256, 2-phase x 3-buffer core): A = Wqkv [1536][512],
// B = xnT [n][c]. blockIdx.y 0-3 -> qT, 4-7 -> kT (trans), 8-11 -> vB.
// grid (4,12,16) = 768 blocks = 3 exact rounds on 256 CUs.
// ==========================================================================
__global__ __launch_bounds__(512, 2) void qkv8_k(
    const unsigned short* __restrict__ Wqkv,
    const unsigned short* __restrict__ xnT,
    unsigned short* __restrict__ qT,
    unsigned short* __restrict__ kT,
    unsigned short* __restrict__ vB,
    const float* __restrict__ bqkv)
{
    __shared__ __align__(16) unsigned short LB[73728];   // 144 KB
    const int z = blockIdx.z;
    const unsigned short* Ab = Wqkv + (long)(blockIdx.y * 128) * 512;
    const unsigned short* Bb = xnT + (long)z * 524288 + (long)(blockIdx.x * 256) * 512;
    f32x4 acc[4][4] = {};
    gemm23_core<8>(Ab, 512, Bb, 512, acc, LB);

    const int lane = threadIdx.x & 63, wave = threadIdx.x >> 6;
    const int wM = wave >> 2, wN = wave & 3;
    const int l16 = lane & 15, quad = lane >> 4;
    const int gm0 = blockIdx.y * 128 + wM * 64;
    const int gn0 = blockIdx.x * 256 + wN * 64;
    const int mat = blockIdx.y >> 2;            // 0=q 1=k 2=v (block-uniform)
    const int ml0 = gm0 & 511;
    const long zb = (long)z * 524288;
    unsigned short* scr = LB + wave * 4096;     // 8 KB per-wave scratch

    if (mat == 2) {
        // natural -> vB[c][j]; scratch [m 64][8 n-chunks of 8], XOR ml&7
        #pragma unroll
        for (int mi = 0; mi < 4; ++mi)
            #pragma unroll
            for (int ni = 0; ni < 4; ++ni) {
                f32x4 v = acc[mi][ni];
                #pragma unroll
                for (int r = 0; r < 4; ++r) {
                    const int ml = mi * 16 + quad * 4 + r;
                    const int nc = ni * 2 + (l16 >> 3);
                    scr[ml * 64 + ((nc ^ (ml & 7)) * 8) + (l16 & 7)] = f2bf(v[r] + bqkv[gm0 + ml]);
                }
            }
        __builtin_amdgcn_s_barrier();   // harmless uniform sync before stores
        const int ch2 = lane & 7, rr = lane >> 3;
        unsigned short* dst = vB + zb + gn0 + ch2 * 8;
        #pragma unroll
        for (int it = 0; it < 8; ++it) {
            const int ml = rr + it * 8;
            uint4 vv = *(uint4*)&scr[ml * 64 + ((ch2 ^ (ml & 7)) * 8)];
            *(uint4*)(dst + (long)(ml0 + ml) * 1024) = vv;
        }
    } else {
        // trans -> qT/kT [i][c]; scratch [n 64][8 m-chunks of 8], XOR nl&7
        unsigned short* dstm = (mat == 0) ? qT : kT;
        #pragma unroll
        for (int mi = 0; mi < 4; ++mi)
            #pragma unroll
            for (int ni = 0; ni < 4; ++ni) {
                f32x4 v = acc[mi][ni];
                const int nl = ni * 16 + l16;
                const int ch = mi * 2 + (quad >> 1);
                const int m4 = gm0 + mi * 16 + quad * 4;
                ushort4 p;
                p.x = f2bf(v[0] + bqkv[m4 + 0]);
                p.y = f2bf(v[1] + bqkv[m4 + 1]);
                p.z = f2bf(v[2] + bqkv[m4 + 2]);
                p.w = f2bf(v[3] + bqkv[m4 + 3]);
                *(ushort4*)&scr[nl * 64 + ((ch ^ (nl & 7)) * 8) + (quad & 1) * 4] = p;
            }
        __builtin_amdgcn_s_barrier();
        const int ch2 = lane & 7, rr = lane >> 3;
        unsigned short* dst = dstm + zb + ml0 + ch2 * 8;
        #pragma unroll
        for (int it = 0; it < 8; ++it) {
            const int nl = rr + it * 8;
            uint4 vv = *(uint4*)&scr[nl * 64 + ((ch2 ^ (nl & 7)) * 8)];
            *(uint4*)(dst + (long)(gn0 + nl) * 512) = vv;
        }
    }
}

// ==========================================================================
// AV gemm (128x256, 2-phase x 3-buffer core, K=1024): O[c][i] =
// sum_j vB[c][j]*Sb[i][j], scaled by 1/Lb[i], transposed -> OT[i][c].
// grid (4,4,16) = 256 blocks = 1 exact round.
// ==========================================================================
__global__ __launch_bounds__(512, 2) void av8_k(
    const unsigned short* __restrict__ vB,
    const unsigned short* __restrict__ Sb,
    unsigned short* __restrict__ OT,
    const float* __restrict__ Lb)
{
    __shared__ __align__(16) unsigned short LB[73728];   // 144 KB
    const int z = blockIdx.z;
    const unsigned short* Ab = vB + (long)z * 524288 + (long)(blockIdx.y * 128) * 1024;
    const unsigned short* Bb = Sb + (long)z * 1048576 + (long)(blockIdx.x * 256) * 1024;
    f32x4 acc[4][4] = {};
    gemm23_core<16>(Ab, 1024, Bb, 1024, acc, LB);

    const int lane = threadIdx.x & 63, wave = threadIdx.x >> 6;
    const int wM = wave >> 2, wN = wave & 3;
    const int l16 = lane & 15, quad = lane >> 4;
    const int gm0 = blockIdx.y * 128 + wM * 64;   // c
    const int gn0 = blockIdx.x * 256 + wN * 64;   // i
    unsigned short* scr = LB + wave * 4096;

    #pragma unroll
    for (int mi = 0; mi < 4; ++mi)
        #pragma unroll
        for (int ni = 0; ni < 4; ++ni) {
            f32x4 v = acc[mi][ni];
            const float invl = 1.f / Lb[(long)z * 1024 + gn0 + ni * 16 + l16];
            const int nl = ni * 16 + l16;
            const int ch = mi * 2 + (quad >> 1);
            ushort4 p;
            p.x = f2bf(v[0] * invl); p.y = f2bf(v[1] * invl);
            p.z = f2bf(v[2] * invl); p.w = f2bf(v[3] * invl);
            *(ushort4*)&scr[nl * 64 + ((ch ^ (nl & 7)) * 8) + (quad & 1) * 4] = p;
        }
    __builtin_amdgcn_s_barrier();
    const int ch2 = lane & 7, rr = lane >> 3;
    unsigned short* dst = OT + (long)z * 524288 + gm0 + ch2 * 8;
    #pragma unroll
    for (int it = 0; it < 8; ++it) {
        const int nl = rr + it * 8;
        uint4 vv = *(uint4*)&scr[nl * 64 + ((ch2 ^ (nl & 7)) * 8)];
        *(uint4*)(dst + (long)(gn0 + nl) * 512) = vv;
    }
}

// ==========================================================================
// ============== 128x128 2-phase core (final fp32 gemm) ====================
// ==========================================================================
__device__ __forceinline__ void stage_tiles(
    const unsigned short* __restrict__ Ab, int lda,
    const unsigned short* __restrict__ Bb, int ldb,
    int k0, unsigned short* Ad, unsigned short* Bd,
    int wave, int r0, int c0)
{
    gl_lds16(Ab + (long)r0 * lda + c0 + k0,        Ad + wave * 512);
    gl_lds16(Ab + (long)(r0 + 64) * lda + c0 + k0, Ad + 2048 + wave * 512);
    gl_lds16(Bb + (long)r0 * ldb + c0 + k0,        Bd + wave * 512);
    gl_lds16(Bb + (long)(r0 + 64) * ldb + c0 + k0, Bd + 2048 + wave * 512);
}

__device__ __forceinline__ void gemm_core_db(
    const unsigned short* __restrict__ Ab, int lda,
    const unsigned short* __restrict__ Bb, int ldb,
    int K, f32x4 (&acc)[4][4],
    unsigned short* As, unsigned short* Bs)   // As[2*4096], Bs[2*4096]
{
    const int tid  = threadIdx.x;
    const int lane = tid & 63;
    const int wave = tid >> 6;
    const int wm   = (wave >> 1) * 64;
    const int wn   = (wave & 1) * 64;
    const int l16  = lane & 15;
    const int quad = lane >> 4;

    const int r0 = wave * 16 + (lane >> 2);
    const int c0 = ((lane & 3) ^ ((lane >> 3) & 3)) * 8;   // source chunk pre-swizzle

    stage_tiles(Ab, lda, Bb, ldb, 0, As, Bs, wave, r0, c0);

    const int sw8 = ((l16 >> 1) & 3) * 8;     // read-side un-swizzle

    int sel = 0;
    for (int k0 = 0; k0 < K; k0 += 32) {
        __syncthreads();
        if (k0 + 32 < K)
            stage_tiles(Ab, lda, Bb, ldb, k0 + 32,
                        As + (sel ^ 1) * 4096, Bs + (sel ^ 1) * 4096, wave, r0, c0);

        const unsigned short* Ap = As + sel * 4096;
        const unsigned short* Bp = Bs + sel * 4096;
        bf16x8 af[4], bfr[4];
        #pragma unroll
        for (int mi = 0; mi < 4; mi++)
            af[mi] = *(const bf16x8*)&Ap[(wm + mi * 16 + l16) * 32 + ((quad * 8) ^ sw8)];
        #pragma unroll
        for (int ni = 0; ni < 4; ni++)
            bfr[ni] = *(const bf16x8*)&Bp[(wn + ni * 16 + l16) * 32 + ((quad * 8) ^ sw8)];
        #pragma unroll
        for (int mi = 0; mi < 4; mi++)
            #pragma unroll
            for (int ni = 0; ni < 4; ni++)
                acc[mi][ni] = __builtin_amdgcn_mfma_f32_16x16x32_bf16(af[mi], bfr[ni], acc[mi][ni], 0, 0, 0);
        sel ^= 1;
    }
}

// final gemm: out = Wp*OT^T + bp + x   (fp32 out, fully coalesced direct)
__global__ __launch_bounds__(256) void fin_k(
    const unsigned short* __restrict__ Wp,
    const unsigned short* __restrict__ OTb,
    float* __restrict__ out,
    const float* __restrict__ bias,
    const float* __restrict__ resid)
{
    __shared__ __align__(16) unsigned short LB[16384];   // 32 KB
    unsigned short* As = LB;
    unsigned short* Bs = LB + 8192;

    const unsigned short* Ab = Wp + (long)(blockIdx.y * 128) * 512;
    const unsigned short* Bb = OTb + (long)blockIdx.z * 524288 + (long)(blockIdx.x * 128) * 512;

    f32x4 acc[4][4] = {};
    gemm_core_db(Ab, 512, Bb, 512, 512, acc, As, Bs);

    const int lane = threadIdx.x & 63;
    const int wave = threadIdx.x >> 6;
    const int l16  = lane & 15;
    const int quad = lane >> 4;
    const int mb = blockIdx.y * 128 + (wave >> 1) * 64;
    const int nb = blockIdx.x * 128 + (wave & 1) * 64;

    #pragma unroll
    for (int mi = 0; mi < 4; mi++) {
        #pragma unroll
        for (int ni = 0; ni < 4; ni++) {
            f32x4 v = acc[mi][ni];
            const int m0 = mb + mi * 16 + quad * 4;
            const int n  = nb + ni * 16 + l16;
            const long base = (long)blockIdx.z * 524288;
            #pragma unroll
            for (int r = 0; r < 4; r++) {
                float val = v[r] + bias[m0 + r] + resid[base + (long)(m0 + r) * 1024 + n];
                out[base + (long)(m0 + r) * 1024 + n] = val;
            }
        }
    }
}

// ==========================================================================
// Merged GroupNorm + weight-conversion kernel (1D grid, 1792 blocks)
// ==========================================================================
__global__ __launch_bounds__(256) void gnw_k(
    const float* __restrict__ x, const float* __restrict__ gsc,
    const float* __restrict__ gbi, unsigned short* __restrict__ xnT,
    const float* __restrict__ w0, const float* __restrict__ w1,
    const float* __restrict__ w2, const float* __restrict__ w3,
    const float* __restrict__ b0, const float* __restrict__ b1,
    const float* __restrict__ b2,
    unsigned short* __restrict__ wout, float* __restrict__ bqkv,
    float* __restrict__ lsum)
{
    __shared__ __align__(16) unsigned short ln[16 * 1024];
    __shared__ float red[8];
    const int bid = blockIdx.x;
    const int tid = threadIdx.x;

    if (bid >= 512) {                       // ---- wconv part ----
        const int j = bid - 512;
        const int m = j >> 8;
        const int i = (j & 255) * 256 + tid;
        if (m == 4) {
            if (i < 384) {
                const int which = i >> 7, off = i & 127;
                const float* src = (which == 0) ? b0 : (which == 1) ? b1 : b2;
                ((float4*)bqkv)[i] = ((const float4*)src)[off];
            }
            if (i < 16384) lsum[i] = 0.f;   // zero [16][1024] row-sum buffer
            return;
        }
        const float* src = (m == 0) ? w0 : (m == 1) ? w1 : (m == 2) ? w2 : w3;
        float4 v = ((const float4*)src)[i];
        ushort4 o; o.x = f2bf(v.x); o.y = f2bf(v.y); o.z = f2bf(v.z); o.w = f2bf(v.w);
        ((ushort4*)(wout + (long)m * 262144))[i] = o;
        return;
    }

    // ---- GN part ----
    const int b = bid >> 5, g = bid & 31;
    const int lane = tid & 63, wv = tid >> 6;

    const float4* x4 = (const float4*)(x + ((long)b * 512 + g * 16) * 1024);
    float4 vals[16];
    float s = 0.f, ss = 0.f;
    #pragma unroll
    for (int i = 0; i < 16; i++) {
        float4 v = x4[tid + i * 256];
        vals[i] = v;
        s  += v.x + v.y + v.z + v.w;
        ss += v.x * v.x + v.y * v.y + v.z * v.z + v.w * v.w;
    }
    for (int o = 32; o; o >>= 1) { s += __shfl_down(s, o); ss += __shfl_down(ss, o); }
    if (lane == 0) { red[wv * 2] = s; red[wv * 2 + 1] = ss; }
    __syncthreads();
    const float S  = red[0] + red[2] + red[4] + red[6];
    const float SS = red[1] + red[3] + red[5] + red[7];
    const float mean = S * (1.f / 16384.f);
    const float var  = SS * (1.f / 16384.f) - mean * mean;
    const float inv  = rsqrtf(var + 1e-5f);

    #pragma unroll
    for (int i = 0; i < 16; i++) {
        const int idx = tid + i * 256;
        const int c   = idx >> 8;
        const float sc = gsc[g * 16 + c] * inv;
        const float bi = gbi[g * 16 + c] - mean * sc;
        float4 v = vals[i];
        ushort4 p;
        p.x = f2bf(v.x * sc + bi); p.y = f2bf(v.y * sc + bi);
        p.z = f2bf(v.z * sc + bi); p.w = f2bf(v.w * sc + bi);
        ((ushort4*)ln)[idx] = p;
    }
    __syncthreads();

    unsigned short* op = xnT + (long)b * 1024 * 512 + g * 16;
    for (int rep = 0; rep < 4; rep++) {
        const int n = rep * 256 + tid;
        union { unsigned short u[16]; uint4 v[2]; } t;
        #pragma unroll
        for (int c = 0; c < 16; c++) t.u[c] = ln[c * 1024 + n];
        *(uint4*)&op[(long)n * 512]     = t.v[0];
        *(uint4*)&op[(long)n * 512 + 8] = t.v[1];
    }
}

// ==========================================================================
extern "C" void kernel_launch(void* const* d_in, const int* in_sizes, int n_in,
                              void* d_out, int out_size, void* d_ws, size_t ws_size,
                              hipStream_t stream)
{
    const float* x   = (const float*)d_in[0];
    const float* gsc = (const float*)d_in[1];
    const float* gbi = (const float*)d_in[2];
    const float* wq  = (const float*)d_in[3];
    const float* bq  = (const float*)d_in[4];
    const float* wk  = (const float*)d_in[5];
    const float* bk  = (const float*)d_in[6];
    const float* wv  = (const float*)d_in[7];
    const float* bv  = (const float*)d_in[8];
    const float* wp  = (const float*)d_in[9];
    const float* bp  = (const float*)d_in[10];
    float* out = (float*)d_out;

    char* ws = (char*)d_ws;
    unsigned short* xnT = (unsigned short*)(ws);               // 16 MB [b][n][c]; reused as OT
    unsigned short* qT  = (unsigned short*)(ws + 16777216);    // 16 MB [b][i][c]
    unsigned short* kT  = (unsigned short*)(ws + 33554432);    // 16 MB [b][j][c]
    unsigned short* vB  = (unsigned short*)(ws + 50331648);    // 16 MB [b][c][j]
    unsigned short* Sb  = (unsigned short*)(ws + 67108864);    // 32 MB [b][i][j] bf16 (P' = exp)
    unsigned short* Wb  = (unsigned short*)(ws + 100663296);   // 2 MB: wq|wk|wv|wp bf16
    float*          bqkv= (float*)        (ws + 102760448);    // 6 KB
    float*          Lb  = (float*)        (ws + 102768640);    // 64 KB [b][i] row sums
    unsigned short* OT  = xnT;

    // GN + weight conversion (merged)
    gnw_k<<<1792, 256, 0, stream>>>(x, gsc, gbi, xnT,
                                    wq, wk, wv, wp, bq, bk, bv, Wb, bqkv, Lb);

    // fused QKV (128x256, 2ph x 3buf, 768 blocks = 3 rounds)
    qkv8_k<<<dim3(4, 12, 16), 512, 0, stream>>>(Wb, xnT, qT, kT, vB, bqkv);

    // P'[i][j] = exp(q·k/sqrt(512)) -> bf16 (256^2 8-phase, 256 blocks)
    p8_k<<<dim3(4, 4, 16), 512, 0, stream>>>(qT, kT, Sb, Lb, 0.044194173824159216f);

    // O = V·P'^T / L -> OT[i][c] (128x256, 2ph x 3buf, K=1024, 256 blocks)
    av8_k<<<dim3(4, 4, 16), 512, 0, stream>>>(vB, Sb, OT, Lb);

    // out = Wp * O + bp + x
    fin_k<<<dim3(8, 4, 16), 256, 0, stream>>>(Wb + 786432, OT, out, bp, x);
}

// Round 7
// 215.852 us; speedup vs baseline: 1.0280x; 1.0280x over previous
//
#include <hip/hip_runtime.h>

// ---------- types ----------
typedef __bf16 bf16x8 __attribute__((ext_vector_type(8)));
typedef float  f32x4  __attribute__((ext_vector_type(4)));

__device__ __forceinline__ unsigned short f2bf(float f) {
    union { float f; unsigned int u; } x; x.f = f;
    unsigned int r = (x.u + 0x7FFFu + ((x.u >> 16) & 1u)) >> 16;  // RNE
    return (unsigned short)r;
}

// async global->LDS, 16B per lane; LDS dst is wave-uniform base + lane*16
typedef const __attribute__((address_space(1))) unsigned short gu16;
typedef __attribute__((address_space(3)))       unsigned short lu16;
__device__ __forceinline__ void gl_lds16(const unsigned short* g, unsigned short* l) {
    __builtin_amdgcn_global_load_lds((gu16*)g, (lu16*)l, 16, 0, 0);
}

// ==========================================================================
// SWIZZLE (both-sides, rule #21). LDS rows are 64 ushorts = 128 B = one
// full bank rotation, so bank depends ONLY on the 16B chunk slot. A wave's
// b128 fragment read (lane = quad q, row = l16) needs uniform slot usage:
// slot(row r, true chunk c) = c ^ (r & 7)  -> 8 lanes/slot = wave64 floor,
// conflict-free. Staging (linear LDS dest): lane writes slot (lane&7) of
// row (lane>>3 mod 8), so the GLOBAL source chunk is (lane&7)^((lane>>3)&7).
// Read: true chunk c = kk*4 + quad -> slot = (kk*4+quad) ^ (l16&7).
// Involution verified: slot holds global chunk slot^(r&7) = c.  [Round-6's
// 1-bit XOR used only 4 of 8 slots -> 2x serialization, 3.4M conflicts.]
// ==========================================================================

// ==========================================================================
// ========= 2-phase x 3-buffer GEMM core: BM=128, BN=256, BK=64 ============
// 8 waves (2M x 4N), 512 threads. LDS 144 KB = 3 buffers x 48 KB:
//   buf*24576: A [128 rows][64 k] (8192 ushorts) | B [256 rows][64 k] (16384)
// Per K-tile: 2 phases x 16 MFMA. Staging DEPTH 2 (tile t+2 staged during
// iter t), counted vmcnt(6) at end of each iter retires exactly tile t+1;
// vmcnt(0) only at iter NT-2.
// ==========================================================================
__device__ __forceinline__ void stageB23(
    const unsigned short* __restrict__ Bb, int ldb,
    unsigned short* LB, int t, int buf, int wave, int lane)
{
    const int kc = t * 64 + (((lane & 7) ^ ((lane >> 3) & 7)) << 3);
    unsigned short* dst = LB + buf * 24576 + 8192 + wave * 512;
    const int R = wave * 8 + (lane >> 3);
    gl_lds16(Bb + (long)R * ldb + kc,         dst);
    gl_lds16(Bb + (long)(R + 64) * ldb + kc,  dst + 4096);
    gl_lds16(Bb + (long)(R + 128) * ldb + kc, dst + 8192);
    gl_lds16(Bb + (long)(R + 192) * ldb + kc, dst + 12288);
}
__device__ __forceinline__ void stageA23(
    const unsigned short* __restrict__ Ab, int lda,
    unsigned short* LB, int t, int buf, int wave, int lane)
{
    const int kc = t * 64 + (((lane & 7) ^ ((lane >> 3) & 7)) << 3);
    unsigned short* dst = LB + buf * 24576 + wave * 512;
    const int R = wave * 8 + (lane >> 3);
    gl_lds16(Ab + (long)R * lda + kc,        dst);
    gl_lds16(Ab + (long)(R + 64) * lda + kc, dst + 4096);
}

template<int NT>   // K-tiles of 64, NT >= 3
__device__ __forceinline__ void gemm23_core(
    const unsigned short* __restrict__ Ab, int lda,
    const unsigned short* __restrict__ Bb, int ldb,
    f32x4 (&acc)[4][4], unsigned short* LB)
{
    const int tid  = threadIdx.x;
    const int lane = tid & 63;
    const int wave = tid >> 6;
    const int wM   = wave >> 2;
    const int wN   = wave & 3;
    const int l16  = lane & 15;
    const int quad = lane >> 4;
    const int ck   = quad ^ (l16 & 7);                   // slot for kk=0; kk=1 -> ck^4
    const int aoff = (wM * 64 + l16) * 64;               // + buf*24576 + mi*1024 + slot*8
    const int boff = 8192 + (wN * 64 + l16) * 64;        // + buf*24576 + ni*1024 + slot*8

    stageB23(Bb, ldb, LB, 0, 0, wave, lane);
    stageA23(Ab, lda, LB, 0, 0, wave, lane);
    stageB23(Bb, ldb, LB, 1, 1, wave, lane);
    stageA23(Ab, lda, LB, 1, 1, wave, lane);
    asm volatile("s_waitcnt vmcnt(6)" ::: "memory");
    __builtin_amdgcn_s_barrier();
    __builtin_amdgcn_sched_barrier(0);

    bf16x8 af[2][2], bf[4][2];

#define RD_A23(buf, mh)                                                       \
    _Pragma("unroll")                                                         \
    for (int m = 0; m < 2; ++m)                                               \
        _Pragma("unroll")                                                     \
        for (int kk = 0; kk < 2; ++kk)                                        \
            af[m][kk] = *(const bf16x8*)&LB[(buf) * 24576 + aoff + ((mh) * 2 + m) * 1024 + ((ck ^ (kk << 2)) << 3)];
#define RD_B23(buf)                                                           \
    _Pragma("unroll")                                                         \
    for (int n = 0; n < 4; ++n)                                               \
        _Pragma("unroll")                                                     \
        for (int kk = 0; kk < 2; ++kk)                                        \
            bf[n][kk] = *(const bf16x8*)&LB[(buf) * 24576 + boff + n * 1024 + ((ck ^ (kk << 2)) << 3)];
#define MF23(mh)                                                              \
    __builtin_amdgcn_s_setprio(1);                                            \
    _Pragma("unroll")                                                         \
    for (int m = 0; m < 2; ++m)                                               \
        _Pragma("unroll")                                                     \
        for (int n = 0; n < 4; ++n)                                           \
            _Pragma("unroll")                                                 \
            for (int kk = 0; kk < 2; ++kk)                                    \
                acc[(mh) * 2 + m][n] = __builtin_amdgcn_mfma_f32_16x16x32_bf16( \
                    af[m][kk], bf[n][kk], acc[(mh) * 2 + m][n], 0, 0, 0);     \
    __builtin_amdgcn_s_setprio(0);
#define BARS23 do { __builtin_amdgcn_s_barrier(); __builtin_amdgcn_sched_barrier(0); } while (0)
#define LGW23  do { asm volatile("s_waitcnt lgkmcnt(0)" ::: "memory"); __builtin_amdgcn_sched_barrier(0); } while (0)

    int b = 0, b2 = 2;
    for (int t = 0; t < NT; ++t) {
        // ---- phase 1: read B + A(mh0) of tile t; stage B of tile t+2
        RD_B23(b) RD_A23(b, 0)
        if (t + 2 < NT) stageB23(Bb, ldb, LB, t + 2, b2, wave, lane);
        BARS23; LGW23;
        MF23(0)                               // 16 MFMA
        BARS23;
        // ---- phase 2: read A(mh1); stage A of tile t+2; counted wait
        RD_A23(b, 1)
        if (t + 2 < NT) stageA23(Ab, lda, LB, t + 2, b2, wave, lane);
        BARS23; LGW23;
        MF23(1)                               // 16 MFMA
        if (t + 2 < NT) { asm volatile("s_waitcnt vmcnt(6)" ::: "memory"); }
        else            { asm volatile("s_waitcnt vmcnt(0)" ::: "memory"); }
        BARS23;
        b  = (b == 2)  ? 0 : b + 1;
        b2 = (b2 == 2) ? 0 : b2 + 1;
    }
#undef RD_A23
#undef RD_B23
#undef MF23
#undef BARS23
#undef LGW23
}

// ==========================================================================
// ============== 8-phase BMH=2 core (p8 only — proven template) ============
// ==========================================================================
template<int NT, int BMH>
__device__ __forceinline__ void stage8g(
    const unsigned short* __restrict__ Ab, int lda,
    const unsigned short* __restrict__ Bb, int ldb,
    unsigned short* LB, int s, int wave, int lane)
{
    if (s >= 4 * NT) return;
    const int tau  = s >> 2;
    const int pi   = s & 3;          // 0:B0 1:B1 2:A0 3:A1
    const int half = pi & 1;
    const int kc   = tau * 64 + (((lane & 7) ^ ((lane >> 3) & 7)) << 3);
    if (pi >= 2) {
        unsigned short* dst = LB + (tau & 1) * (BMH * 8192) + half * (BMH * 4096) + wave * 512;
        const int R = half * (BMH * 64) + wave * 8 + (lane >> 3);
        gl_lds16(Ab + (long)R * lda + kc, dst);
        if constexpr (BMH == 2) gl_lds16(Ab + (long)(R + 64) * lda + kc, dst + 4096);
    } else {
        unsigned short* dst = LB + (BMH * 16384) + (tau & 1) * 16384 + half * 8192 + wave * 512;
        const int R = half * 128 + wave * 8 + (lane >> 3);
        gl_lds16(Bb + (long)R * ldb + kc, dst);
        gl_lds16(Bb + (long)(R + 64) * ldb + kc, dst + 4096);
    }
}

template<int NT, int BMH>   // NT = K/64, even
__device__ __forceinline__ void gemm8_core(
    const unsigned short* __restrict__ Ab, int lda,
    const unsigned short* __restrict__ Bb, int ldb,
    f32x4 (&acc)[4 * BMH][4], unsigned short* LB)
{
    const int tid  = threadIdx.x;
    const int lane = tid & 63;
    const int wave = tid >> 6;
    const int wM   = wave >> 2;
    const int wN   = wave & 3;
    const int l16  = lane & 15;
    const int quad = lane >> 4;
    const int ck   = quad ^ (l16 & 7);                   // slot for kk=0; kk=1 -> ck^4
    const int aoff = wM * (BMH * 4096) + l16 * 64;
    const int boff = BMH * 16384 + (wN >> 1) * 8192 + ((wN & 1) * 64 + l16) * 64;

#define VMW do { if constexpr (BMH == 2) asm volatile("s_waitcnt vmcnt(6)" ::: "memory"); \
                 else                    asm volatile("s_waitcnt vmcnt(5)" ::: "memory"); } while (0)

    #pragma unroll
    for (int s = 0; s < 7; ++s)
        stage8g<NT, BMH>(Ab, lda, Bb, ldb, LB, s, wave, lane);
    VMW;
    __builtin_amdgcn_s_barrier();
    __builtin_amdgcn_sched_barrier(0);

    bf16x8 af[2 * BMH][2], bf[4][2];

#define RD_A(buf, mh)                                                         \
    _Pragma("unroll")                                                         \
    for (int m = 0; m < 2 * BMH; ++m)                                         \
        _Pragma("unroll")                                                     \
        for (int kk = 0; kk < 2; ++kk)                                        \
            af[m][kk] = *(const bf16x8*)&LB[(buf) * (BMH * 8192) + aoff + ((mh) * 2 * BMH + m) * 1024 + ((ck ^ (kk << 2)) << 3)];
#define RD_B(buf)                                                             \
    _Pragma("unroll")                                                         \
    for (int n = 0; n < 4; ++n)                                               \
        _Pragma("unroll")                                                     \
        for (int kk = 0; kk < 2; ++kk)                                        \
            bf[n][kk] = *(const bf16x8*)&LB[(buf) * 16384 + boff + n * 1024 + ((ck ^ (kk << 2)) << 3)];
#define MF(mh, nh)                                                            \
    __builtin_amdgcn_s_setprio(1);                                            \
    _Pragma("unroll")                                                         \
    for (int m = 0; m < 2 * BMH; ++m)                                         \
        _Pragma("unroll")                                                     \
        for (int n = 0; n < 2; ++n)                                           \
            _Pragma("unroll")                                                 \
            for (int kk = 0; kk < 2; ++kk)                                    \
                acc[(mh) * 2 * BMH + m][(nh) * 2 + n] = __builtin_amdgcn_mfma_f32_16x16x32_bf16( \
                    af[m][kk], bf[(nh) * 2 + n][kk], acc[(mh) * 2 * BMH + m][(nh) * 2 + n], 0, 0, 0); \
    __builtin_amdgcn_s_setprio(0);
#define BARS do { __builtin_amdgcn_s_barrier(); __builtin_amdgcn_sched_barrier(0); } while (0)
#define LGW  do { asm volatile("s_waitcnt lgkmcnt(0)" ::: "memory"); __builtin_amdgcn_sched_barrier(0); } while (0)

    const int NITER = NT / 2;
    for (int i = 0; i < NITER; ++i) {
        const int s0 = 6 + 8 * i;
        RD_B(0) RD_A(0, 0)
        stage8g<NT, BMH>(Ab, lda, Bb, ldb, LB, s0 + 1, wave, lane);
        BARS; LGW;
        MF(0, 0)
        BARS;
        stage8g<NT, BMH>(Ab, lda, Bb, ldb, LB, s0 + 2, wave, lane);
        BARS;
        MF(0, 1)
        BARS;
        RD_A(0, 1)
        stage8g<NT, BMH>(Ab, lda, Bb, ldb, LB, s0 + 3, wave, lane);
        BARS; LGW;
        MF(1, 0)
        BARS;
        stage8g<NT, BMH>(Ab, lda, Bb, ldb, LB, s0 + 4, wave, lane);
        BARS;
        MF(1, 1)
        if (i == NITER - 1) { asm volatile("s_waitcnt vmcnt(0)" ::: "memory"); }
        else                { VMW; }
        BARS;
        RD_B(1) RD_A(1, 0)
        stage8g<NT, BMH>(Ab, lda, Bb, ldb, LB, s0 + 5, wave, lane);
        BARS; LGW;
        MF(0, 0)
        BARS;
        stage8g<NT, BMH>(Ab, lda, Bb, ldb, LB, s0 + 6, wave, lane);
        BARS;
        MF(0, 1)
        BARS;
        RD_A(1, 1)
        stage8g<NT, BMH>(Ab, lda, Bb, ldb, LB, s0 + 7, wave, lane);
        BARS; LGW;
        MF(1, 0)
        BARS;
        stage8g<NT, BMH>(Ab, lda, Bb, ldb, LB, s0 + 8, wave, lane);
        BARS;
        MF(1, 1)
        if (i < NITER - 1) { VMW; }
        BARS;
    }
#undef RD_A
#undef RD_B
#undef MF
#undef BARS
#undef LGW
#undef VMW
}

// ==========================================================================
// P' kernel (256^2 8-phase): Sb[i][j] = exp(alpha * q.k), row sums -> lsum
// grid (4,4,16) = 256 blocks, 512 threads.
// ==========================================================================
__global__ __launch_bounds__(512, 2) void p8_k(
    const unsigned short* __restrict__ qT,
    const unsigned short* __restrict__ kT,
    unsigned short* __restrict__ Sb,
    float* __restrict__ lsum,
    float alpha)
{
    __shared__ __align__(16) unsigned short LB[65536];
    const int z = blockIdx.z;
    const unsigned short* Ab = qT + (long)z * 524288 + (long)(blockIdx.y * 256) * 512;
    const unsigned short* Bb = kT + (long)z * 524288 + (long)(blockIdx.x * 256) * 512;
    f32x4 acc[8][4] = {};
    gemm8_core<8, 2>(Ab, 512, Bb, 512, acc, LB);

    const int lane = threadIdx.x & 63, wave = threadIdx.x >> 6;
    const int wM = wave >> 2, wN = wave & 3;
    const int l16 = lane & 15, quad = lane >> 4;
    const int gm0 = blockIdx.y * 256 + wM * 128;
    const int gn0 = blockIdx.x * 256 + wN * 64;
    unsigned short* scr = LB + wave * 8192;     // 128 rows x 64 ushort, chunk-XOR

    float rs[8][4];
    #pragma unroll
    for (int mi = 0; mi < 8; ++mi) { rs[mi][0] = rs[mi][1] = rs[mi][2] = rs[mi][3] = 0.f; }
    #pragma unroll
    for (int mi = 0; mi < 8; ++mi)
        #pragma unroll
        for (int ni = 0; ni < 4; ++ni) {
            f32x4 v = acc[mi][ni];
            #pragma unroll
            for (int r = 0; r < 4; ++r) {
                float e = __expf(v[r] * alpha);
                rs[mi][r] += e;
                const int row = mi * 16 + quad * 4 + r;
                const int col = ni * 16 + l16;
                scr[row * 64 + (((col >> 3) ^ (row & 7)) << 3) + (col & 7)] = f2bf(e);
            }
        }
    #pragma unroll
    for (int mi = 0; mi < 8; ++mi)
        #pragma unroll
        for (int r = 0; r < 4; ++r) {
            float s = rs[mi][r];
            s += __shfl_xor(s, 1); s += __shfl_xor(s, 2);
            s += __shfl_xor(s, 4); s += __shfl_xor(s, 8);
            if (l16 == 0)
                atomicAdd(&lsum[(long)z * 1024 + gm0 + mi * 16 + quad * 4 + r], s);
        }
    unsigned short* dst = Sb + (long)z * 1048576;
    #pragma unroll
    for (int it = 0; it < 16; ++it) {
        const int row = it * 8 + (lane >> 3);
        const int ck2 = lane & 7;
        uint4 vv = *(uint4*)&scr[row * 64 + ((ck2 ^ (row & 7)) << 3)];
        *(uint4*)&dst[(long)(gm0 + row) * 1024 + gn0 + ck2 * 8] = vv;
    }
}

// ==========================================================================
// Fused QKV (128x256, 2-phase x 3-buffer core): A = Wqkv [1536][512],
// B = xnT [n][c]. blockIdx.y 0-3 -> qT, 4-7 -> kT (trans), 8-11 -> vB.
// grid (4,12,16) = 768 blocks = 3 exact rounds on 256 CUs.
// ==========================================================================
__global__ __launch_bounds__(512, 2) void qkv8_k(
    const unsigned short* __restrict__ Wqkv,
    const unsigned short* __restrict__ xnT,
    unsigned short* __restrict__ qT,
    unsigned short* __restrict__ kT,
    unsigned short* __restrict__ vB,
    const float* __restrict__ bqkv)
{
    __shared__ __align__(16) unsigned short LB[73728];   // 144 KB
    const int z = blockIdx.z;
    const unsigned short* Ab = Wqkv + (long)(blockIdx.y * 128) * 512;
    const unsigned short* Bb = xnT + (long)z * 524288 + (long)(blockIdx.x * 256) * 512;
    f32x4 acc[4][4] = {};
    gemm23_core<8>(Ab, 512, Bb, 512, acc, LB);

    const int lane = threadIdx.x & 63, wave = threadIdx.x >> 6;
    const int wM = wave >> 2, wN = wave & 3;
    const int l16 = lane & 15, quad = lane >> 4;
    const int gm0 = blockIdx.y * 128 + wM * 64;
    const int gn0 = blockIdx.x * 256 + wN * 64;
    const int mat = blockIdx.y >> 2;            // 0=q 1=k 2=v (block-uniform)
    const int ml0 = gm0 & 511;
    const long zb = (long)z * 524288;
    unsigned short* scr = LB + wave * 4096;     // 8 KB per-wave scratch

    if (mat == 2) {
        // natural -> vB[c][j]; scratch [m 64][8 n-chunks of 8], XOR ml&7
        #pragma unroll
        for (int mi = 0; mi < 4; ++mi)
            #pragma unroll
            for (int ni = 0; ni < 4; ++ni) {
                f32x4 v = acc[mi][ni];
                #pragma unroll
                for (int r = 0; r < 4; ++r) {
                    const int ml = mi * 16 + quad * 4 + r;
                    const int nc = ni * 2 + (l16 >> 3);
                    scr[ml * 64 + ((nc ^ (ml & 7)) * 8) + (l16 & 7)] = f2bf(v[r] + bqkv[gm0 + ml]);
                }
            }
        __builtin_amdgcn_s_barrier();   // uniform sync before stores
        const int ch2 = lane & 7, rr = lane >> 3;
        unsigned short* dst = vB + zb + gn0 + ch2 * 8;
        #pragma unroll
        for (int it = 0; it < 8; ++it) {
            const int ml = rr + it * 8;
            uint4 vv = *(uint4*)&scr[ml * 64 + ((ch2 ^ (ml & 7)) * 8)];
            *(uint4*)(dst + (long)(ml0 + ml) * 1024) = vv;
        }
    } else {
        // trans -> qT/kT [i][c]; scratch [n 64][8 m-chunks of 8], XOR nl&7
        unsigned short* dstm = (mat == 0) ? qT : kT;
        #pragma unroll
        for (int mi = 0; mi < 4; ++mi)
            #pragma unroll
            for (int ni = 0; ni < 4; ++ni) {
                f32x4 v = acc[mi][ni];
                const int nl = ni * 16 + l16;
                const int ch = mi * 2 + (quad >> 1);
                const int m4 = gm0 + mi * 16 + quad * 4;
                ushort4 p;
                p.x = f2bf(v[0] + bqkv[m4 + 0]);
                p.y = f2bf(v[1] + bqkv[m4 + 1]);
                p.z = f2bf(v[2] + bqkv[m4 + 2]);
                p.w = f2bf(v[3] + bqkv[m4 + 3]);
                *(ushort4*)&scr[nl * 64 + ((ch ^ (nl & 7)) * 8) + (quad & 1) * 4] = p;
            }
        __builtin_amdgcn_s_barrier();
        const int ch2 = lane & 7, rr = lane >> 3;
        unsigned short* dst = dstm + zb + ml0 + ch2 * 8;
        #pragma unroll
        for (int it = 0; it < 8; ++it) {
            const int nl = rr + it * 8;
            uint4 vv = *(uint4*)&scr[nl * 64 + ((ch2 ^ (nl & 7)) * 8)];
            *(uint4*)(dst + (long)(gn0 + nl) * 512) = vv;
        }
    }
}

// ==========================================================================
// AV gemm (128x256, 2-phase x 3-buffer core, K=1024): O[c][i] =
// sum_j vB[c][j]*Sb[i][j], scaled by 1/Lb[i], transposed -> OT[i][c].
// grid (4,4,16) = 256 blocks = 1 exact round.
// ==========================================================================
__global__ __launch_bounds__(512, 2) void av8_k(
    const unsigned short* __restrict__ vB,
    const unsigned short* __restrict__ Sb,
    unsigned short* __restrict__ OT,
    const float* __restrict__ Lb)
{
    __shared__ __align__(16) unsigned short LB[73728];   // 144 KB
    const int z = blockIdx.z;
    const unsigned short* Ab = vB + (long)z * 524288 + (long)(blockIdx.y * 128) * 1024;
    const unsigned short* Bb = Sb + (long)z * 1048576 + (long)(blockIdx.x * 256) * 1024;
    f32x4 acc[4][4] = {};
    gemm23_core<16>(Ab, 1024, Bb, 1024, acc, LB);

    const int lane = threadIdx.x & 63, wave = threadIdx.x >> 6;
    const int wM = wave >> 2, wN = wave & 3;
    const int l16 = lane & 15, quad = lane >> 4;
    const int gm0 = blockIdx.y * 128 + wM * 64;   // c
    const int gn0 = blockIdx.x * 256 + wN * 64;   // i
    unsigned short* scr = LB + wave * 4096;

    #pragma unroll
    for (int mi = 0; mi < 4; ++mi)
        #pragma unroll
        for (int ni = 0; ni < 4; ++ni) {
            f32x4 v = acc[mi][ni];
            const float invl = 1.f / Lb[(long)z * 1024 + gn0 + ni * 16 + l16];
            const int nl = ni * 16 + l16;
            const int ch = mi * 2 + (quad >> 1);
            ushort4 p;
            p.x = f2bf(v[0] * invl); p.y = f2bf(v[1] * invl);
            p.z = f2bf(v[2] * invl); p.w = f2bf(v[3] * invl);
            *(ushort4*)&scr[nl * 64 + ((ch ^ (nl & 7)) * 8) + (quad & 1) * 4] = p;
        }
    __builtin_amdgcn_s_barrier();
    const int ch2 = lane & 7, rr = lane >> 3;
    unsigned short* dst = OT + (long)z * 524288 + gm0 + ch2 * 8;
    #pragma unroll
    for (int it = 0; it < 8; ++it) {
        const int nl = rr + it * 8;
        uint4 vv = *(uint4*)&scr[nl * 64 + ((ch2 ^ (nl & 7)) * 8)];
        *(uint4*)(dst + (long)(gn0 + nl) * 512) = vv;
    }
}

// ==========================================================================
// ============== 128x128 2-phase core (final fp32 gemm) ====================
// ==========================================================================
__device__ __forceinline__ void stage_tiles(
    const unsigned short* __restrict__ Ab, int lda,
    const unsigned short* __restrict__ Bb, int ldb,
    int k0, unsigned short* Ad, unsigned short* Bd,
    int wave, int r0, int c0)
{
    gl_lds16(Ab + (long)r0 * lda + c0 + k0,        Ad + wave * 512);
    gl_lds16(Ab + (long)(r0 + 64) * lda + c0 + k0, Ad + 2048 + wave * 512);
    gl_lds16(Bb + (long)r0 * ldb + c0 + k0,        Bd + wave * 512);
    gl_lds16(Bb + (long)(r0 + 64) * ldb + c0 + k0, Bd + 2048 + wave * 512);
}

__device__ __forceinline__ void gemm_core_db(
    const unsigned short* __restrict__ Ab, int lda,
    const unsigned short* __restrict__ Bb, int ldb,
    int K, f32x4 (&acc)[4][4],
    unsigned short* As, unsigned short* Bs)   // As[2*4096], Bs[2*4096]
{
    const int tid  = threadIdx.x;
    const int lane = tid & 63;
    const int wave = tid >> 6;
    const int wm   = (wave >> 1) * 64;
    const int wn   = (wave & 1) * 64;
    const int l16  = lane & 15;
    const int quad = lane >> 4;

    const int r0 = wave * 16 + (lane >> 2);
    const int c0 = ((lane & 3) ^ ((lane >> 3) & 3)) * 8;   // source chunk pre-swizzle

    stage_tiles(Ab, lda, Bb, ldb, 0, As, Bs, wave, r0, c0);

    const int sw8 = ((l16 >> 1) & 3) * 8;     // read-side un-swizzle

    int sel = 0;
    for (int k0 = 0; k0 < K; k0 += 32) {
        __syncthreads();
        if (k0 + 32 < K)
            stage_tiles(Ab, lda, Bb, ldb, k0 + 32,
                        As + (sel ^ 1) * 4096, Bs + (sel ^ 1) * 4096, wave, r0, c0);

        const unsigned short* Ap = As + sel * 4096;
        const unsigned short* Bp = Bs + sel * 4096;
        bf16x8 af[4], bfr[4];
        #pragma unroll
        for (int mi = 0; mi < 4; mi++)
            af[mi] = *(const bf16x8*)&Ap[(wm + mi * 16 + l16) * 32 + ((quad * 8) ^ sw8)];
        #pragma unroll
        for (int ni = 0; ni < 4; ni++)
            bfr[ni] = *(const bf16x8*)&Bp[(wn + ni * 16 + l16) * 32 + ((quad * 8) ^ sw8)];
        #pragma unroll
        for (int mi = 0; mi < 4; mi++)
            #pragma unroll
            for (int ni = 0; ni < 4; ni++)
                acc[mi][ni] = __builtin_amdgcn_mfma_f32_16x16x32_bf16(af[mi], bfr[ni], acc[mi][ni], 0, 0, 0);
        sel ^= 1;
    }
}

// final gemm: out = Wp*OT^T + bp + x   (fp32 out, fully coalesced direct)
__global__ __launch_bounds__(256) void fin_k(
    const unsigned short* __restrict__ Wp,
    const unsigned short* __restrict__ OTb,
    float* __restrict__ out,
    const float* __restrict__ bias,
    const float* __restrict__ resid)
{
    __shared__ __align__(16) unsigned short LB[16384];   // 32 KB
    unsigned short* As = LB;
    unsigned short* Bs = LB + 8192;

    const unsigned short* Ab = Wp + (long)(blockIdx.y * 128) * 512;
    const unsigned short* Bb = OTb + (long)blockIdx.z * 524288 + (long)(blockIdx.x * 128) * 512;

    f32x4 acc[4][4] = {};
    gemm_core_db(Ab, 512, Bb, 512, 512, acc, As, Bs);

    const int lane = threadIdx.x & 63;
    const int wave = threadIdx.x >> 6;
    const int l16  = lane & 15;
    const int quad = lane >> 4;
    const int mb = blockIdx.y * 128 + (wave >> 1) * 64;
    const int nb = blockIdx.x * 128 + (wave & 1) * 64;

    #pragma unroll
    for (int mi = 0; mi < 4; mi++) {
        #pragma unroll
        for (int ni = 0; ni < 4; ni++) {
            f32x4 v = acc[mi][ni];
            const int m0 = mb + mi * 16 + quad * 4;
            const int n  = nb + ni * 16 + l16;
            const long base = (long)blockIdx.z * 524288;
            #pragma unroll
            for (int r = 0; r < 4; r++) {
                float val = v[r] + bias[m0 + r] + resid[base + (long)(m0 + r) * 1024 + n];
                out[base + (long)(m0 + r) * 1024 + n] = val;
            }
        }
    }
}

// ==========================================================================
// Merged GroupNorm + weight-conversion kernel (1D grid, 1792 blocks)
// ==========================================================================
__global__ __launch_bounds__(256) void gnw_k(
    const float* __restrict__ x, const float* __restrict__ gsc,
    const float* __restrict__ gbi, unsigned short* __restrict__ xnT,
    const float* __restrict__ w0, const float* __restrict__ w1,
    const float* __restrict__ w2, const float* __restrict__ w3,
    const float* __restrict__ b0, const float* __restrict__ b1,
    const float* __restrict__ b2,
    unsigned short* __restrict__ wout, float* __restrict__ bqkv,
    float* __restrict__ lsum)
{
    __shared__ __align__(16) unsigned short ln[16 * 1024];
    __shared__ float red[8];
    const int bid = blockIdx.x;
    const int tid = threadIdx.x;

    if (bid >= 512) {                       // ---- wconv part ----
        const int j = bid - 512;
        const int m = j >> 8;
        const int i = (j & 255) * 256 + tid;
        if (m == 4) {
            if (i < 384) {
                const int which = i >> 7, off = i & 127;
                const float* src = (which == 0) ? b0 : (which == 1) ? b1 : b2;
                ((float4*)bqkv)[i] = ((const float4*)src)[off];
            }
            if (i < 16384) lsum[i] = 0.f;   // zero [16][1024] row-sum buffer
            return;
        }
        const float* src = (m == 0) ? w0 : (m == 1) ? w1 : (m == 2) ? w2 : w3;
        float4 v = ((const float4*)src)[i];
        ushort4 o; o.x = f2bf(v.x); o.y = f2bf(v.y); o.z = f2bf(v.z); o.w = f2bf(v.w);
        ((ushort4*)(wout + (long)m * 262144))[i] = o;
        return;
    }

    // ---- GN part ----
    const int b = bid >> 5, g = bid & 31;
    const int lane = tid & 63, wv = tid >> 6;

    const float4* x4 = (const float4*)(x + ((long)b * 512 + g * 16) * 1024);
    float4 vals[16];
    float s = 0.f, ss = 0.f;
    #pragma unroll
    for (int i = 0; i < 16; i++) {
        float4 v = x4[tid + i * 256];
        vals[i] = v;
        s  += v.x + v.y + v.z + v.w;
        ss += v.x * v.x + v.y * v.y + v.z * v.z + v.w * v.w;
    }
    for (int o = 32; o; o >>= 1) { s += __shfl_down(s, o); ss += __shfl_down(ss, o); }
    if (lane == 0) { red[wv * 2] = s; red[wv * 2 + 1] = ss; }
    __syncthreads();
    const float S  = red[0] + red[2] + red[4] + red[6];
    const float SS = red[1] + red[3] + red[5] + red[7];
    const float mean = S * (1.f / 16384.f);
    const float var  = SS * (1.f / 16384.f) - mean * mean;
    const float inv  = rsqrtf(var + 1e-5f);

    #pragma unroll
    for (int i = 0; i < 16; i++) {
        const int idx = tid + i * 256;
        const int c   = idx >> 8;
        const float sc = gsc[g * 16 + c] * inv;
        const float bi = gbi[g * 16 + c] - mean * sc;
        float4 v = vals[i];
        ushort4 p;
        p.x = f2bf(v.x * sc + bi); p.y = f2bf(v.y * sc + bi);
        p.z = f2bf(v.z * sc + bi); p.w = f2bf(v.w * sc + bi);
        ((ushort4*)ln)[idx] = p;
    }
    __syncthreads();

    unsigned short* op = xnT + (long)b * 1024 * 512 + g * 16;
    for (int rep = 0; rep < 4; rep++) {
        const int n = rep * 256 + tid;
        union { unsigned short u[16]; uint4 v[2]; } t;
        #pragma unroll
        for (int c = 0; c < 16; c++) t.u[c] = ln[c * 1024 + n];
        *(uint4*)&op[(long)n * 512]     = t.v[0];
        *(uint4*)&op[(long)n * 512 + 8] = t.v[1];
    }
}

// ==========================================================================
extern "C" void kernel_launch(void* const* d_in, const int* in_sizes, int n_in,
                              void* d_out, int out_size, void* d_ws, size_t ws_size,
                              hipStream_t stream)
{
    const float* x   = (const float*)d_in[0];
    const float* gsc = (const float*)d_in[1];
    const float* gbi = (const float*)d_in[2];
    const float* wq  = (const float*)d_in[3];
    const float* bq  = (const float*)d_in[4];
    const float* wk  = (const float*)d_in[5];
    const float* bk  = (const float*)d_in[6];
    const float* wv  = (const float*)d_in[7];
    const float* bv  = (const float*)d_in[8];
    const float* wp  = (const float*)d_in[9];
    const float* bp  = (const float*)d_in[10];
    float* out = (float*)d_out;

    char* ws = (char*)d_ws;
    unsigned short* xnT = (unsigned short*)(ws);               // 16 MB [b][n][c]; reused as OT
    unsigned short* qT  = (unsigned short*)(ws + 16777216);    // 16 MB [b][i][c]
    unsigned short* kT  = (unsigned short*)(ws + 33554432);    // 16 MB [b][j][c]
    unsigned short* vB  = (unsigned short*)(ws + 50331648);    // 16 MB [b][c][j]
    unsigned short* Sb  = (unsigned short*)(ws + 67108864);    // 32 MB [b][i][j] bf16 (P' = exp)
    unsigned short* Wb  = (unsigned short*)(ws + 100663296);   // 2 MB: wq|wk|wv|wp bf16
    float*          bqkv= (float*)        (ws + 102760448);    // 6 KB
    float*          Lb  = (float*)        (ws + 102768640);    // 64 KB [b][i] row sums
    unsigned short* OT  = xnT;

    // GN + weight conversion (merged)
    gnw_k<<<1792, 256, 0, stream>>>(x, gsc, gbi, xnT,
                                    wq, wk, wv, wp, bq, bk, bv, Wb, bqkv, Lb);

    // fused QKV (128x256, 2ph x 3buf, 768 blocks = 3 rounds)
    qkv8_k<<<dim3(4, 12, 16), 512, 0, stream>>>(Wb, xnT, qT, kT, vB, bqkv);

    // P'[i][j] = exp(q·k/sqrt(512)) -> bf16 (256^2 8-phase, 256 blocks)
    p8_k<<<dim3(4, 4, 16), 512, 0, stream>>>(qT, kT, Sb, Lb, 0.044194173824159216f);

    // O = V·P'^T / L -> OT[i][c] (128x256, 2ph x 3buf, K=1024, 256 blocks)
    av8_k<<<dim3(4, 4, 16), 512, 0, stream>>>(vB, Sb, OT, Lb);

    // out = Wp * O + bp + x
    fin_k<<<dim3(8, 4, 16), 256, 0, stream>>>(Wb + 786432, OT, out, bp, x);
}

// Round 8
// 215.789 us; speedup vs baseline: 1.0283x; 1.0003x over previous
//
#include <hip/hip_runtime.h>

// ---------- types ----------
typedef __bf16 bf16x8 __attribute__((ext_vector_type(8)));
typedef float  f32x4  __attribute__((ext_vector_type(4)));

__device__ __forceinline__ unsigned short f2bf(float f) {
    union { float f; unsigned int u; } x; x.f = f;
    unsigned int r = (x.u + 0x7FFFu + ((x.u >> 16) & 1u)) >> 16;  // RNE
    return (unsigned short)r;
}

// async global->LDS, 16B per lane; LDS dst is wave-uniform base + lane*16
typedef const __attribute__((address_space(1))) unsigned short gu16;
typedef __attribute__((address_space(3)))       unsigned short lu16;
__device__ __forceinline__ void gl_lds16(const unsigned short* g, unsigned short* l) {
    __builtin_amdgcn_global_load_lds((gu16*)g, (lu16*)l, 16, 0, 0);
}

// ==========================================================================
// SWIZZLE (both-sides, rule #21). LDS rows are 64 ushorts = 128 B = one
// full bank rotation, so bank depends ONLY on the 16B chunk slot.
// slot(row r, true chunk c) = c ^ (r & 7)  -> 8 lanes/slot = wave64 floor.
// Staging (linear LDS dest): GLOBAL source chunk = (lane&7)^((lane>>3)&7).
// Read: true chunk c = kk*4 + quad -> slot = (kk*4+quad) ^ (l16&7).
// ==========================================================================

// ==========================================================================
// ==== 1-phase x 3-buffer GEMM core: BM=128, BN=256, BK=64 (merged) ========
// 8 waves (2M x 4N), 512 threads. LDS 144 KB = 3 buffers x 48 KB:
//   buf*24576: A [128 rows][64 k] (8192 ushorts) | B [256 rows][64 k] (16384)
// ONE phase per K-tile: {read all 16 b128 frags + issue 6 stage loads for
// tile t+2; barrier; lgkmcnt(0); 32 MFMA; counted vmcnt; barrier}.
// Barriers/tile: 2 (was 4) -> 2x MFMA per barrier period (310 SIMD-cyc).
// FIFO ledger: end of tile t outstanding = t+1(6) + t+2(6) = 12 ->
// vmcnt(6) retires exactly tile t+1; at t = NT-2 nothing staged ->
// vmcnt(0) drains tile NT-1. Buffer hazard: t+2 writes buf (t+2)%3 = buf
// of t-1, whose last read finished two barriers ago.
// ==========================================================================
__device__ __forceinline__ void stageB23(
    const unsigned short* __restrict__ Bb, int ldb,
    unsigned short* LB, int t, int buf, int wave, int lane)
{
    const int kc = t * 64 + (((lane & 7) ^ ((lane >> 3) & 7)) << 3);
    unsigned short* dst = LB + buf * 24576 + 8192 + wave * 512;
    const int R = wave * 8 + (lane >> 3);
    gl_lds16(Bb + (long)R * ldb + kc,         dst);
    gl_lds16(Bb + (long)(R + 64) * ldb + kc,  dst + 4096);
    gl_lds16(Bb + (long)(R + 128) * ldb + kc, dst + 8192);
    gl_lds16(Bb + (long)(R + 192) * ldb + kc, dst + 12288);
}
__device__ __forceinline__ void stageA23(
    const unsigned short* __restrict__ Ab, int lda,
    unsigned short* LB, int t, int buf, int wave, int lane)
{
    const int kc = t * 64 + (((lane & 7) ^ ((lane >> 3) & 7)) << 3);
    unsigned short* dst = LB + buf * 24576 + wave * 512;
    const int R = wave * 8 + (lane >> 3);
    gl_lds16(Ab + (long)R * lda + kc,        dst);
    gl_lds16(Ab + (long)(R + 64) * lda + kc, dst + 4096);
}

template<int NT>   // K-tiles of 64, NT >= 3
__device__ __forceinline__ void gemm23_core(
    const unsigned short* __restrict__ Ab, int lda,
    const unsigned short* __restrict__ Bb, int ldb,
    f32x4 (&acc)[4][4], unsigned short* LB)
{
    const int tid  = threadIdx.x;
    const int lane = tid & 63;
    const int wave = tid >> 6;
    const int wM   = wave >> 2;
    const int wN   = wave & 3;
    const int l16  = lane & 15;
    const int quad = lane >> 4;
    const int ck   = quad ^ (l16 & 7);                   // slot for kk=0; kk=1 -> ck^4
    const int aoff = (wM * 64 + l16) * 64;               // + buf*24576 + mi*1024 + slot*8
    const int boff = 8192 + (wN * 64 + l16) * 64;        // + buf*24576 + ni*1024 + slot*8

    stageB23(Bb, ldb, LB, 0, 0, wave, lane);
    stageA23(Ab, lda, LB, 0, 0, wave, lane);
    stageB23(Bb, ldb, LB, 1, 1, wave, lane);
    stageA23(Ab, lda, LB, 1, 1, wave, lane);
    asm volatile("s_waitcnt vmcnt(6)" ::: "memory");
    __builtin_amdgcn_s_barrier();
    __builtin_amdgcn_sched_barrier(0);

    bf16x8 af[4][2], bf[4][2];

#define RD_ALL(buf)                                                           \
    _Pragma("unroll")                                                         \
    for (int n = 0; n < 4; ++n)                                               \
        _Pragma("unroll")                                                     \
        for (int kk = 0; kk < 2; ++kk)                                        \
            bf[n][kk] = *(const bf16x8*)&LB[(buf) * 24576 + boff + n * 1024 + ((ck ^ (kk << 2)) << 3)]; \
    _Pragma("unroll")                                                         \
    for (int m = 0; m < 4; ++m)                                               \
        _Pragma("unroll")                                                     \
        for (int kk = 0; kk < 2; ++kk)                                        \
            af[m][kk] = *(const bf16x8*)&LB[(buf) * 24576 + aoff + m * 1024 + ((ck ^ (kk << 2)) << 3)];
#define MF32                                                                  \
    __builtin_amdgcn_s_setprio(1);                                            \
    _Pragma("unroll")                                                         \
    for (int m = 0; m < 4; ++m)                                               \
        _Pragma("unroll")                                                     \
        for (int n = 0; n < 4; ++n)                                           \
            _Pragma("unroll")                                                 \
            for (int kk = 0; kk < 2; ++kk)                                    \
                acc[m][n] = __builtin_amdgcn_mfma_f32_16x16x32_bf16(          \
                    af[m][kk], bf[n][kk], acc[m][n], 0, 0, 0);                \
    __builtin_amdgcn_s_setprio(0);

    int b = 0, b2 = 2;
    for (int t = 0; t < NT; ++t) {
        // read all fragments of tile t; issue stage of tile t+2
        RD_ALL(b)
        if (t + 2 < NT) {
            stageB23(Bb, ldb, LB, t + 2, b2, wave, lane);
            stageA23(Ab, lda, LB, t + 2, b2, wave, lane);
        }
        __builtin_amdgcn_s_barrier();
        __builtin_amdgcn_sched_barrier(0);
        asm volatile("s_waitcnt lgkmcnt(0)" ::: "memory");
        __builtin_amdgcn_sched_barrier(0);
        MF32                                   // 32 MFMA
        if (t + 2 < NT) { asm volatile("s_waitcnt vmcnt(6)" ::: "memory"); }
        else            { asm volatile("s_waitcnt vmcnt(0)" ::: "memory"); }
        __builtin_amdgcn_s_barrier();
        __builtin_amdgcn_sched_barrier(0);
        b  = (b == 2)  ? 0 : b + 1;
        b2 = (b2 == 2) ? 0 : b2 + 1;
    }
#undef RD_ALL
#undef MF32
}

// ==========================================================================
// ============== 8-phase BMH=2 core (p8 only — unchanged control) ==========
// ==========================================================================
template<int NT, int BMH>
__device__ __forceinline__ void stage8g(
    const unsigned short* __restrict__ Ab, int lda,
    const unsigned short* __restrict__ Bb, int ldb,
    unsigned short* LB, int s, int wave, int lane)
{
    if (s >= 4 * NT) return;
    const int tau  = s >> 2;
    const int pi   = s & 3;          // 0:B0 1:B1 2:A0 3:A1
    const int half = pi & 1;
    const int kc   = tau * 64 + (((lane & 7) ^ ((lane >> 3) & 7)) << 3);
    if (pi >= 2) {
        unsigned short* dst = LB + (tau & 1) * (BMH * 8192) + half * (BMH * 4096) + wave * 512;
        const int R = half * (BMH * 64) + wave * 8 + (lane >> 3);
        gl_lds16(Ab + (long)R * lda + kc, dst);
        if constexpr (BMH == 2) gl_lds16(Ab + (long)(R + 64) * lda + kc, dst + 4096);
    } else {
        unsigned short* dst = LB + (BMH * 16384) + (tau & 1) * 16384 + half * 8192 + wave * 512;
        const int R = half * 128 + wave * 8 + (lane >> 3);
        gl_lds16(Bb + (long)R * ldb + kc, dst);
        gl_lds16(Bb + (long)(R + 64) * ldb + kc, dst + 4096);
    }
}

template<int NT, int BMH>   // NT = K/64, even
__device__ __forceinline__ void gemm8_core(
    const unsigned short* __restrict__ Ab, int lda,
    const unsigned short* __restrict__ Bb, int ldb,
    f32x4 (&acc)[4 * BMH][4], unsigned short* LB)
{
    const int tid  = threadIdx.x;
    const int lane = tid & 63;
    const int wave = tid >> 6;
    const int wM   = wave >> 2;
    const int wN   = wave & 3;
    const int l16  = lane & 15;
    const int quad = lane >> 4;
    const int ck   = quad ^ (l16 & 7);
    const int aoff = wM * (BMH * 4096) + l16 * 64;
    const int boff = BMH * 16384 + (wN >> 1) * 8192 + ((wN & 1) * 64 + l16) * 64;

#define VMW do { if constexpr (BMH == 2) asm volatile("s_waitcnt vmcnt(6)" ::: "memory"); \
                 else                    asm volatile("s_waitcnt vmcnt(5)" ::: "memory"); } while (0)

    #pragma unroll
    for (int s = 0; s < 7; ++s)
        stage8g<NT, BMH>(Ab, lda, Bb, ldb, LB, s, wave, lane);
    VMW;
    __builtin_amdgcn_s_barrier();
    __builtin_amdgcn_sched_barrier(0);

    bf16x8 af[2 * BMH][2], bf[4][2];

#define RD_A(buf, mh)                                                         \
    _Pragma("unroll")                                                         \
    for (int m = 0; m < 2 * BMH; ++m)                                         \
        _Pragma("unroll")                                                     \
        for (int kk = 0; kk < 2; ++kk)                                        \
            af[m][kk] = *(const bf16x8*)&LB[(buf) * (BMH * 8192) + aoff + ((mh) * 2 * BMH + m) * 1024 + ((ck ^ (kk << 2)) << 3)];
#define RD_B(buf)                                                             \
    _Pragma("unroll")                                                         \
    for (int n = 0; n < 4; ++n)                                               \
        _Pragma("unroll")                                                     \
        for (int kk = 0; kk < 2; ++kk)                                        \
            bf[n][kk] = *(const bf16x8*)&LB[(buf) * 16384 + boff + n * 1024 + ((ck ^ (kk << 2)) << 3)];
#define MF(mh, nh)                                                            \
    __builtin_amdgcn_s_setprio(1);                                            \
    _Pragma("unroll")                                                         \
    for (int m = 0; m < 2 * BMH; ++m)                                         \
        _Pragma("unroll")                                                     \
        for (int n = 0; n < 2; ++n)                                           \
            _Pragma("unroll")                                                 \
            for (int kk = 0; kk < 2; ++kk)                                    \
                acc[(mh) * 2 * BMH + m][(nh) * 2 + n] = __builtin_amdgcn_mfma_f32_16x16x32_bf16( \
                    af[m][kk], bf[(nh) * 2 + n][kk], acc[(mh) * 2 * BMH + m][(nh) * 2 + n], 0, 0, 0); \
    __builtin_amdgcn_s_setprio(0);
#define BARS do { __builtin_amdgcn_s_barrier(); __builtin_amdgcn_sched_barrier(0); } while (0)
#define LGW  do { asm volatile("s_waitcnt lgkmcnt(0)" ::: "memory"); __builtin_amdgcn_sched_barrier(0); } while (0)

    const int NITER = NT / 2;
    for (int i = 0; i < NITER; ++i) {
        const int s0 = 6 + 8 * i;
        RD_B(0) RD_A(0, 0)
        stage8g<NT, BMH>(Ab, lda, Bb, ldb, LB, s0 + 1, wave, lane);
        BARS; LGW;
        MF(0, 0)
        BARS;
        stage8g<NT, BMH>(Ab, lda, Bb, ldb, LB, s0 + 2, wave, lane);
        BARS;
        MF(0, 1)
        BARS;
        RD_A(0, 1)
        stage8g<NT, BMH>(Ab, lda, Bb, ldb, LB, s0 + 3, wave, lane);
        BARS; LGW;
        MF(1, 0)
        BARS;
        stage8g<NT, BMH>(Ab, lda, Bb, ldb, LB, s0 + 4, wave, lane);
        BARS;
        MF(1, 1)
        if (i == NITER - 1) { asm volatile("s_waitcnt vmcnt(0)" ::: "memory"); }
        else                { VMW; }
        BARS;
        RD_B(1) RD_A(1, 0)
        stage8g<NT, BMH>(Ab, lda, Bb, ldb, LB, s0 + 5, wave, lane);
        BARS; LGW;
        MF(0, 0)
        BARS;
        stage8g<NT, BMH>(Ab, lda, Bb, ldb, LB, s0 + 6, wave, lane);
        BARS;
        MF(0, 1)
        BARS;
        RD_A(1, 1)
        stage8g<NT, BMH>(Ab, lda, Bb, ldb, LB, s0 + 7, wave, lane);
        BARS; LGW;
        MF(1, 0)
        BARS;
        stage8g<NT, BMH>(Ab, lda, Bb, ldb, LB, s0 + 8, wave, lane);
        BARS;
        MF(1, 1)
        if (i < NITER - 1) { VMW; }
        BARS;
    }
#undef RD_A
#undef RD_B
#undef MF
#undef BARS
#undef LGW
#undef VMW
}

// ==========================================================================
// P' kernel (256^2 8-phase): Sb[i][j] = exp(alpha * q.k), row sums -> lsum
// grid (4,4,16) = 256 blocks, 512 threads.
// ==========================================================================
__global__ __launch_bounds__(512, 2) void p8_k(
    const unsigned short* __restrict__ qT,
    const unsigned short* __restrict__ kT,
    unsigned short* __restrict__ Sb,
    float* __restrict__ lsum,
    float alpha)
{
    __shared__ __align__(16) unsigned short LB[65536];
    const int z = blockIdx.z;
    const unsigned short* Ab = qT + (long)z * 524288 + (long)(blockIdx.y * 256) * 512;
    const unsigned short* Bb = kT + (long)z * 524288 + (long)(blockIdx.x * 256) * 512;
    f32x4 acc[8][4] = {};
    gemm8_core<8, 2>(Ab, 512, Bb, 512, acc, LB);

    const int lane = threadIdx.x & 63, wave = threadIdx.x >> 6;
    const int wM = wave >> 2, wN = wave & 3;
    const int l16 = lane & 15, quad = lane >> 4;
    const int gm0 = blockIdx.y * 256 + wM * 128;
    const int gn0 = blockIdx.x * 256 + wN * 64;
    unsigned short* scr = LB + wave * 8192;     // 128 rows x 64 ushort, chunk-XOR

    float rs[8][4];
    #pragma unroll
    for (int mi = 0; mi < 8; ++mi) { rs[mi][0] = rs[mi][1] = rs[mi][2] = rs[mi][3] = 0.f; }
    #pragma unroll
    for (int mi = 0; mi < 8; ++mi)
        #pragma unroll
        for (int ni = 0; ni < 4; ++ni) {
            f32x4 v = acc[mi][ni];
            #pragma unroll
            for (int r = 0; r < 4; ++r) {
                float e = __expf(v[r] * alpha);
                rs[mi][r] += e;
                const int row = mi * 16 + quad * 4 + r;
                const int col = ni * 16 + l16;
                scr[row * 64 + (((col >> 3) ^ (row & 7)) << 3) + (col & 7)] = f2bf(e);
            }
        }
    #pragma unroll
    for (int mi = 0; mi < 8; ++mi)
        #pragma unroll
        for (int r = 0; r < 4; ++r) {
            float s = rs[mi][r];
            s += __shfl_xor(s, 1); s += __shfl_xor(s, 2);
            s += __shfl_xor(s, 4); s += __shfl_xor(s, 8);
            if (l16 == 0)
                atomicAdd(&lsum[(long)z * 1024 + gm0 + mi * 16 + quad * 4 + r], s);
        }
    unsigned short* dst = Sb + (long)z * 1048576;
    #pragma unroll
    for (int it = 0; it < 16; ++it) {
        const int row = it * 8 + (lane >> 3);
        const int ck2 = lane & 7;
        uint4 vv = *(uint4*)&scr[row * 64 + ((ck2 ^ (row & 7)) << 3)];
        *(uint4*)&dst[(long)(gm0 + row) * 1024 + gn0 + ck2 * 8] = vv;
    }
}

// ==========================================================================
// Fused QKV (128x256, 1-phase x 3-buffer core): A = Wqkv [1536][512],
// B = xnT [n][c]. blockIdx.y 0-3 -> qT, 4-7 -> kT (trans), 8-11 -> vB.
// grid (4,12,16) = 768 blocks = 3 exact rounds on 256 CUs.
// ==========================================================================
__global__ __launch_bounds__(512, 2) void qkv8_k(
    const unsigned short* __restrict__ Wqkv,
    const unsigned short* __restrict__ xnT,
    unsigned short* __restrict__ qT,
    unsigned short* __restrict__ kT,
    unsigned short* __restrict__ vB,
    const float* __restrict__ bqkv)
{
    __shared__ __align__(16) unsigned short LB[73728];   // 144 KB
    const int z = blockIdx.z;
    const unsigned short* Ab = Wqkv + (long)(blockIdx.y * 128) * 512;
    const unsigned short* Bb = xnT + (long)z * 524288 + (long)(blockIdx.x * 256) * 512;
    f32x4 acc[4][4] = {};
    gemm23_core<8>(Ab, 512, Bb, 512, acc, LB);

    const int lane = threadIdx.x & 63, wave = threadIdx.x >> 6;
    const int wM = wave >> 2, wN = wave & 3;
    const int l16 = lane & 15, quad = lane >> 4;
    const int gm0 = blockIdx.y * 128 + wM * 64;
    const int gn0 = blockIdx.x * 256 + wN * 64;
    const int mat = blockIdx.y >> 2;            // 0=q 1=k 2=v (block-uniform)
    const int ml0 = gm0 & 511;
    const long zb = (long)z * 524288;
    unsigned short* scr = LB + wave * 4096;     // 8 KB per-wave scratch

    if (mat == 2) {
        // natural -> vB[c][j]; scratch [m 64][8 n-chunks of 8], XOR ml&7
        #pragma unroll
        for (int mi = 0; mi < 4; ++mi)
            #pragma unroll
            for (int ni = 0; ni < 4; ++ni) {
                f32x4 v = acc[mi][ni];
                #pragma unroll
                for (int r = 0; r < 4; ++r) {
                    const int ml = mi * 16 + quad * 4 + r;
                    const int nc = ni * 2 + (l16 >> 3);
                    scr[ml * 64 + ((nc ^ (ml & 7)) * 8) + (l16 & 7)] = f2bf(v[r] + bqkv[gm0 + ml]);
                }
            }
        __builtin_amdgcn_s_barrier();   // uniform sync before stores
        const int ch2 = lane & 7, rr = lane >> 3;
        unsigned short* dst = vB + zb + gn0 + ch2 * 8;
        #pragma unroll
        for (int it = 0; it < 8; ++it) {
            const int ml = rr + it * 8;
            uint4 vv = *(uint4*)&scr[ml * 64 + ((ch2 ^ (ml & 7)) * 8)];
            *(uint4*)(dst + (long)(ml0 + ml) * 1024) = vv;
        }
    } else {
        // trans -> qT/kT [i][c]; scratch [n 64][8 m-chunks of 8], XOR nl&7
        unsigned short* dstm = (mat == 0) ? qT : kT;
        #pragma unroll
        for (int mi = 0; mi < 4; ++mi)
            #pragma unroll
            for (int ni = 0; ni < 4; ++ni) {
                f32x4 v = acc[mi][ni];
                const int nl = ni * 16 + l16;
                const int ch = mi * 2 + (quad >> 1);
                const int m4 = gm0 + mi * 16 + quad * 4;
                ushort4 p;
                p.x = f2bf(v[0] + bqkv[m4 + 0]);
                p.y = f2bf(v[1] + bqkv[m4 + 1]);
                p.z = f2bf(v[2] + bqkv[m4 + 2]);
                p.w = f2bf(v[3] + bqkv[m4 + 3]);
                *(ushort4*)&scr[nl * 64 + ((ch ^ (nl & 7)) * 8) + (quad & 1) * 4] = p;
            }
        __builtin_amdgcn_s_barrier();
        const int ch2 = lane & 7, rr = lane >> 3;
        unsigned short* dst = dstm + zb + ml0 + ch2 * 8;
        #pragma unroll
        for (int it = 0; it < 8; ++it) {
            const int nl = rr + it * 8;
            uint4 vv = *(uint4*)&scr[nl * 64 + ((ch2 ^ (nl & 7)) * 8)];
            *(uint4*)(dst + (long)(gn0 + nl) * 512) = vv;
        }
    }
}

// ==========================================================================
// AV gemm (128x256, 1-phase x 3-buffer core, K=1024): O[c][i] =
// sum_j vB[c][j]*Sb[i][j], scaled by 1/Lb[i], transposed -> OT[i][c].
// grid (4,4,16) = 256 blocks = 1 exact round.
// ==========================================================================
__global__ __launch_bounds__(512, 2) void av8_k(
    const unsigned short* __restrict__ vB,
    const unsigned short* __restrict__ Sb,
    unsigned short* __restrict__ OT,
    const float* __restrict__ Lb)
{
    __shared__ __align__(16) unsigned short LB[73728];   // 144 KB
    const int z = blockIdx.z;
    const unsigned short* Ab = vB + (long)z * 524288 + (long)(blockIdx.y * 128) * 1024;
    const unsigned short* Bb = Sb + (long)z * 1048576 + (long)(blockIdx.x * 256) * 1024;
    f32x4 acc[4][4] = {};
    gemm23_core<16>(Ab, 1024, Bb, 1024, acc, LB);

    const int lane = threadIdx.x & 63, wave = threadIdx.x >> 6;
    const int wM = wave >> 2, wN = wave & 3;
    const int l16 = lane & 15, quad = lane >> 4;
    const int gm0 = blockIdx.y * 128 + wM * 64;   // c
    const int gn0 = blockIdx.x * 256 + wN * 64;   // i
    unsigned short* scr = LB + wave * 4096;

    #pragma unroll
    for (int mi = 0; mi < 4; ++mi)
        #pragma unroll
        for (int ni = 0; ni < 4; ++ni) {
            f32x4 v = acc[mi][ni];
            const float invl = 1.f / Lb[(long)z * 1024 + gn0 + ni * 16 + l16];
            const int nl = ni * 16 + l16;
            const int ch = mi * 2 + (quad >> 1);
            ushort4 p;
            p.x = f2bf(v[0] * invl); p.y = f2bf(v[1] * invl);
            p.z = f2bf(v[2] * invl); p.w = f2bf(v[3] * invl);
            *(ushort4*)&scr[nl * 64 + ((ch ^ (nl & 7)) * 8) + (quad & 1) * 4] = p;
        }
    __builtin_amdgcn_s_barrier();
    const int ch2 = lane & 7, rr = lane >> 3;
    unsigned short* dst = OT + (long)z * 524288 + gm0 + ch2 * 8;
    #pragma unroll
    for (int it = 0; it < 8; ++it) {
        const int nl = rr + it * 8;
        uint4 vv = *(uint4*)&scr[nl * 64 + ((ch2 ^ (nl & 7)) * 8)];
        *(uint4*)(dst + (long)(gn0 + nl) * 512) = vv;
    }
}

// ==========================================================================
// ============== 128x128 2-phase core (final fp32 gemm) ====================
// ==========================================================================
__device__ __forceinline__ void stage_tiles(
    const unsigned short* __restrict__ Ab, int lda,
    const unsigned short* __restrict__ Bb, int ldb,
    int k0, unsigned short* Ad, unsigned short* Bd,
    int wave, int r0, int c0)
{
    gl_lds16(Ab + (long)r0 * lda + c0 + k0,        Ad + wave * 512);
    gl_lds16(Ab + (long)(r0 + 64) * lda + c0 + k0, Ad + 2048 + wave * 512);
    gl_lds16(Bb + (long)r0 * ldb + c0 + k0,        Bd + wave * 512);
    gl_lds16(Bb + (long)(r0 + 64) * ldb + c0 + k0, Bd + 2048 + wave * 512);
}

__device__ __forceinline__ void gemm_core_db(
    const unsigned short* __restrict__ Ab, int lda,
    const unsigned short* __restrict__ Bb, int ldb,
    int K, f32x4 (&acc)[4][4],
    unsigned short* As, unsigned short* Bs)   // As[2*4096], Bs[2*4096]
{
    const int tid  = threadIdx.x;
    const int lane = tid & 63;
    const int wave = tid >> 6;
    const int wm   = (wave >> 1) * 64;
    const int wn   = (wave & 1) * 64;
    const int l16  = lane & 15;
    const int quad = lane >> 4;

    const int r0 = wave * 16 + (lane >> 2);
    const int c0 = ((lane & 3) ^ ((lane >> 3) & 3)) * 8;   // source chunk pre-swizzle

    stage_tiles(Ab, lda, Bb, ldb, 0, As, Bs, wave, r0, c0);

    const int sw8 = ((l16 >> 1) & 3) * 8;     // read-side un-swizzle

    int sel = 0;
    for (int k0 = 0; k0 < K; k0 += 32) {
        __syncthreads();
        if (k0 + 32 < K)
            stage_tiles(Ab, lda, Bb, ldb, k0 + 32,
                        As + (sel ^ 1) * 4096, Bs + (sel ^ 1) * 4096, wave, r0, c0);

        const unsigned short* Ap = As + sel * 4096;
        const unsigned short* Bp = Bs + sel * 4096;
        bf16x8 af[4], bfr[4];
        #pragma unroll
        for (int mi = 0; mi < 4; mi++)
            af[mi] = *(const bf16x8*)&Ap[(wm + mi * 16 + l16) * 32 + ((quad * 8) ^ sw8)];
        #pragma unroll
        for (int ni = 0; ni < 4; ni++)
            bfr[ni] = *(const bf16x8*)&Bp[(wn + ni * 16 + l16) * 32 + ((quad * 8) ^ sw8)];
        #pragma unroll
        for (int mi = 0; mi < 4; mi++)
            #pragma unroll
            for (int ni = 0; ni < 4; ni++)
                acc[mi][ni] = __builtin_amdgcn_mfma_f32_16x16x32_bf16(af[mi], bfr[ni], acc[mi][ni], 0, 0, 0);
        sel ^= 1;
    }
}

// final gemm: out = Wp*OT^T + bp + x   (fp32 out, fully coalesced direct)
__global__ __launch_bounds__(256) void fin_k(
    const unsigned short* __restrict__ Wp,
    const unsigned short* __restrict__ OTb,
    float* __restrict__ out,
    const float* __restrict__ bias,
    const float* __restrict__ resid)
{
    __shared__ __align__(16) unsigned short LB[16384];   // 32 KB
    unsigned short* As = LB;
    unsigned short* Bs = LB + 8192;

    const unsigned short* Ab = Wp + (long)(blockIdx.y * 128) * 512;
    const unsigned short* Bb = OTb + (long)blockIdx.z * 524288 + (long)(blockIdx.x * 128) * 512;

    f32x4 acc[4][4] = {};
    gemm_core_db(Ab, 512, Bb, 512, 512, acc, As, Bs);

    const int lane = threadIdx.x & 63;
    const int wave = threadIdx.x >> 6;
    const int l16  = lane & 15;
    const int quad = lane >> 4;
    const int mb = blockIdx.y * 128 + (wave >> 1) * 64;
    const int nb = blockIdx.x * 128 + (wave & 1) * 64;

    #pragma unroll
    for (int mi = 0; mi < 4; mi++) {
        #pragma unroll
        for (int ni = 0; ni < 4; ni++) {
            f32x4 v = acc[mi][ni];
            const int m0 = mb + mi * 16 + quad * 4;
            const int n  = nb + ni * 16 + l16;
            const long base = (long)blockIdx.z * 524288;
            #pragma unroll
            for (int r = 0; r < 4; r++) {
                float val = v[r] + bias[m0 + r] + resid[base + (long)(m0 + r) * 1024 + n];
                out[base + (long)(m0 + r) * 1024 + n] = val;
            }
        }
    }
}

// ==========================================================================
// Merged GroupNorm + weight-conversion kernel (1D grid, 1792 blocks)
// ==========================================================================
__global__ __launch_bounds__(256) void gnw_k(
    const float* __restrict__ x, const float* __restrict__ gsc,
    const float* __restrict__ gbi, unsigned short* __restrict__ xnT,
    const float* __restrict__ w0, const float* __restrict__ w1,
    const float* __restrict__ w2, const float* __restrict__ w3,
    const float* __restrict__ b0, const float* __restrict__ b1,
    const float* __restrict__ b2,
    unsigned short* __restrict__ wout, float* __restrict__ bqkv,
    float* __restrict__ lsum)
{
    __shared__ __align__(16) unsigned short ln[16 * 1024];
    __shared__ float red[8];
    const int bid = blockIdx.x;
    const int tid = threadIdx.x;

    if (bid >= 512) {                       // ---- wconv part ----
        const int j = bid - 512;
        const int m = j >> 8;
        const int i = (j & 255) * 256 + tid;
        if (m == 4) {
            if (i < 384) {
                const int which = i >> 7, off = i & 127;
                const float* src = (which == 0) ? b0 : (which == 1) ? b1 : b2;
                ((float4*)bqkv)[i] = ((const float4*)src)[off];
            }
            if (i < 16384) lsum[i] = 0.f;   // zero [16][1024] row-sum buffer
            return;
        }
        const float* src = (m == 0) ? w0 : (m == 1) ? w1 : (m == 2) ? w2 : w3;
        float4 v = ((const float4*)src)[i];
        ushort4 o; o.x = f2bf(v.x); o.y = f2bf(v.y); o.z = f2bf(v.z); o.w = f2bf(v.w);
        ((ushort4*)(wout + (long)m * 262144))[i] = o;
        return;
    }

    // ---- GN part ----
    const int b = bid >> 5, g = bid & 31;
    const int lane = tid & 63, wv = tid >> 6;

    const float4* x4 = (const float4*)(x + ((long)b * 512 + g * 16) * 1024);
    float4 vals[16];
    float s = 0.f, ss = 0.f;
    #pragma unroll
    for (int i = 0; i < 16; i++) {
        float4 v = x4[tid + i * 256];
        vals[i] = v;
        s  += v.x + v.y + v.z + v.w;
        ss += v.x * v.x + v.y * v.y + v.z * v.z + v.w * v.w;
    }
    for (int o = 32; o; o >>= 1) { s += __shfl_down(s, o); ss += __shfl_down(ss, o); }
    if (lane == 0) { red[wv * 2] = s; red[wv * 2 + 1] = ss; }
    __syncthreads();
    const float S  = red[0] + red[2] + red[4] + red[6];
    const float SS = red[1] + red[3] + red[5] + red[7];
    const float mean = S * (1.f / 16384.f);
    const float var  = SS * (1.f / 16384.f) - mean * mean;
    const float inv  = rsqrtf(var + 1e-5f);

    #pragma unroll
    for (int i = 0; i < 16; i++) {
        const int idx = tid + i * 256;
        const int c   = idx >> 8;
        const float sc = gsc[g * 16 + c] * inv;
        const float bi = gbi[g * 16 + c] - mean * sc;
        float4 v = vals[i];
        ushort4 p;
        p.x = f2bf(v.x * sc + bi); p.y = f2bf(v.y * sc + bi);
        p.z = f2bf(v.z * sc + bi); p.w = f2bf(v.w * sc + bi);
        ((ushort4*)ln)[idx] = p;
    }
    __syncthreads();

    unsigned short* op = xnT + (long)b * 1024 * 512 + g * 16;
    for (int rep = 0; rep < 4; rep++) {
        const int n = rep * 256 + tid;
        union { unsigned short u[16]; uint4 v[2]; } t;
        #pragma unroll
        for (int c = 0; c < 16; c++) t.u[c] = ln[c * 1024 + n];
        *(uint4*)&op[(long)n * 512]     = t.v[0];
        *(uint4*)&op[(long)n * 512 + 8] = t.v[1];
    }
}

// ==========================================================================
extern "C" void kernel_launch(void* const* d_in, const int* in_sizes, int n_in,
                              void* d_out, int out_size, void* d_ws, size_t ws_size,
                              hipStream_t stream)
{
    const float* x   = (const float*)d_in[0];
    const float* gsc = (const float*)d_in[1];
    const float* gbi = (const float*)d_in[2];
    const float* wq  = (const float*)d_in[3];
    const float* bq  = (const float*)d_in[4];
    const float* wk  = (const float*)d_in[5];
    const float* bk  = (const float*)d_in[6];
    const float* wv  = (const float*)d_in[7];
    const float* bv  = (const float*)d_in[8];
    const float* wp  = (const float*)d_in[9];
    const float* bp  = (const float*)d_in[10];
    float* out = (float*)d_out;

    char* ws = (char*)d_ws;
    unsigned short* xnT = (unsigned short*)(ws);               // 16 MB [b][n][c]; reused as OT
    unsigned short* qT  = (unsigned short*)(ws + 16777216);    // 16 MB [b][i][c]
    unsigned short* kT  = (unsigned short*)(ws + 33554432);    // 16 MB [b][j][c]
    unsigned short* vB  = (unsigned short*)(ws + 50331648);    // 16 MB [b][c][j]
    unsigned short* Sb  = (unsigned short*)(ws + 67108864);    // 32 MB [b][i][j] bf16 (P' = exp)
    unsigned short* Wb  = (unsigned short*)(ws + 100663296);   // 2 MB: wq|wk|wv|wp bf16
    float*          bqkv= (float*)        (ws + 102760448);    // 6 KB
    float*          Lb  = (float*)        (ws + 102768640);    // 64 KB [b][i] row sums
    unsigned short* OT  = xnT;

    // GN + weight conversion (merged)
    gnw_k<<<1792, 256, 0, stream>>>(x, gsc, gbi, xnT,
                                    wq, wk, wv, wp, bq, bk, bv, Wb, bqkv, Lb);

    // fused QKV (128x256, 1ph x 3buf, 768 blocks = 3 rounds)
    qkv8_k<<<dim3(4, 12, 16), 512, 0, stream>>>(Wb, xnT, qT, kT, vB, bqkv);

    // P'[i][j] = exp(q·k/sqrt(512)) -> bf16 (256^2 8-phase, 256 blocks)
    p8_k<<<dim3(4, 4, 16), 512, 0, stream>>>(qT, kT, Sb, Lb, 0.044194173824159216f);

    // O = V·P'^T / L -> OT[i][c] (128x256, 1ph x 3buf, K=1024, 256 blocks)
    av8_k<<<dim3(4, 4, 16), 512, 0, stream>>>(vB, Sb, OT, Lb);

    // out = Wp * O + bp + x
    fin_k<<<dim3(8, 4, 16), 256, 0, stream>>>(Wb + 786432, OT, out, bp, x);
}